// Round 12
// baseline (1701.604 us; speedup 1.0000x reference)
//
#include <hip/hip_runtime.h>
#include <stdint.h>

// ---------------------------------------------------------------------------
// Block_44074954391877: ViT mixed block (temporal attn + spatial attn + MLP)
// B=4, T=8, N=196, C=1024, HEADS=16, HD=64, HIDDEN=4096
// Strategy: bf16 MFMA (16x16x32) for all GEMMs AND spatial attention, f32
// accumulate. GEMM = R2 structure (2-barrier, BK=32) + conflict-free LDS
// swizzle (R5) + bijective XCD-chunked block swizzle (R7/m204 general form).
// R12: GEMMs are LDS-READ-BOUND (8 b128/wave/K-step = 384 cyc vs 77 cyc
// MFMA -> predicted 20% MfmaUtil == observed; invariant across R2-R5
// scheduling variants). Fix: wide-N GEMMs (qkv x2, fc1) use TN=256 ->
// wave tile 64x128 -> 12 b128 per 32 MFMAs (-25% LDS bytes/FLOP).
// TILE POLICY: TM=64/TN=128 ONLY for grid-starved N=1024 GEMMs
// (fused-temporal, s_proj, fc2 -- R8/R9/R10).
// GELU = tanh-form fast approx (R9). Wcomb = Wfc*Wp fusion (R6).
// build_x2+ln2 fused (R8). Prep fused + attn_a vectorized (R11).
// ---------------------------------------------------------------------------

#define SCALE 0.125f

typedef unsigned short u16;
typedef short bf16x8 __attribute__((ext_vector_type(8)));
typedef float f32x4 __attribute__((ext_vector_type(4)));

static constexpr int kNT    = 1568;     // N*T
static constexpr int kRowsA = 6272;     // B*N*T (temporal rows)
static constexpr int kSeqS  = 197;      // N+1 (spatial seq len)
static constexpr int kRowsS = 6304;     // B*T*197
static constexpr int kRowsC = 6276;     // B*1569 (x2 rows)
static constexpr size_t kXO = 6422528;  // elements of xo output

__device__ __forceinline__ float bf2f(u16 u) {
    union { unsigned int i; float f; } c; c.i = ((unsigned int)u) << 16; return c.f;
}
__device__ __forceinline__ u16 f2bf(float f) {
    union { float f; unsigned int i; } c; c.f = f;
    unsigned int r = c.i + 0x7FFFu + ((c.i >> 16) & 1u);  // RNE
    return (u16)(r >> 16);
}

// async global->LDS, 16B per lane; dst must be wave-uniform base (HW adds lane*16)
__device__ __forceinline__ void gll16(const void* g, void* l) {
    __builtin_amdgcn_global_load_lds((__attribute__((address_space(1))) void*)g,
                                     (__attribute__((address_space(3))) void*)l,
                                     16, 0, 0);
}

// fast GELU (tanh form): v*e/(1+e), e = exp(2z), z = v*(0.79788456+0.03567741*v*v)
__device__ __forceinline__ float gelu_fast(float v) {
    const float zz = 2.f * v * (0.79788456f + 0.03567741f * v * v);
    const float e = __expf(fminf(zz, 40.f));
    return v * e / (1.f + e);
}

// ---------------------------------------------------------------------------
// Fused f32 -> bf16 weight conversion: 6 jobs in ONE launch (R11).
// ---------------------------------------------------------------------------
struct ConvJob { const float* src; u16* dst; int n4; };
struct ConvJobs6 { ConvJob j[6]; };

__global__ void convw6_k(ConvJobs6 jobs) {
    const int stride = gridDim.x * blockDim.x;
    const int t0 = blockIdx.x * blockDim.x + threadIdx.x;
#pragma unroll
    for (int k = 0; k < 6; ++k) {
        const float* __restrict__ in = jobs.j[k].src;
        u16* __restrict__ out = jobs.j[k].dst;
        const int n4 = jobs.j[k].n4;
        for (int i = t0; i < n4; i += stride) {
            float4 v = ((const float4*)in)[i];
            ushort4 o;
            o.x = f2bf(v.x); o.y = f2bf(v.y); o.z = f2bf(v.z); o.w = f2bf(v.w);
            ((ushort4*)out)[i] = o;
        }
    }
}

// 1024x1024 f32 -> bf16 TRANSPOSE (out[k][j] = in[j][k]) for Wcomb prep
__global__ void transpose_bf_k(const float* __restrict__ in, u16* __restrict__ out) {
    __shared__ float t[16][17];
    const int tx = threadIdx.x & 15, ty = threadIdx.x >> 4;
    const int bx = blockIdx.x, by = blockIdx.y;
    t[ty][tx] = in[(size_t)(by * 16 + ty) * 1024 + bx * 16 + tx];
    __syncthreads();
    out[(size_t)(bx * 16 + ty) * 1024 + by * 16 + tx] = f2bf(t[tx][ty]);
}

// bcomb[o] = sum_j fcw[o][j]*bp[j] + fcb[o]  (f32; one wave per row)
__global__ void bcomb_k(const float* __restrict__ fcw, const float* __restrict__ bp,
                        const float* __restrict__ fcb, float* __restrict__ out) {
    const int row = blockIdx.x * 4 + (threadIdx.x >> 6);
    const int lane = threadIdx.x & 63;
    float s = 0.f;
#pragma unroll
    for (int i = 0; i < 16; ++i)
        s += fcw[(size_t)row * 1024 + (i << 6) + lane] * bp[(i << 6) + lane];
#pragma unroll
    for (int off = 1; off < 64; off <<= 1) s += __shfl_xor(s, off);
    if (lane == 0) out[row] = s + fcb[row];
}

// both bias3072 vectors in one launch: [qb | zeros | vb] for temporal+spatial
__global__ void bias3x2_k(const float* __restrict__ qbt, const float* __restrict__ vbt,
                          const float* __restrict__ qbs, const float* __restrict__ vbs,
                          float* __restrict__ dt, float* __restrict__ ds) {
    const int i = blockIdx.x * 256 + threadIdx.x;
    if (i >= 3072) return;
    dt[i] = (i < 1024) ? qbt[i] : (i < 2048) ? 0.0f : vbt[i - 2048];
    ds[i] = (i < 1024) ? qbs[i] : (i < 2048) ? 0.0f : vbs[i - 2048];
}

// ---------------------------------------------------------------------------
// LayerNorm (one wave per row of 1024), gathers per stage, writes bf16.
// MODE 0: temporal (src=x, row r=b*1568+n*8+t  <- x[b][t][n][:])
// MODE 1: spatial  (src=xt_f, src2=cls_token; r=s2*197+i)
// ---------------------------------------------------------------------------
template<int MODE>
__global__ void ln_k(const float* __restrict__ src, const float* __restrict__ src2,
                     const float* __restrict__ g, const float* __restrict__ bt,
                     u16* __restrict__ out, int rows) {
    const int r = (blockIdx.x << 2) + (threadIdx.x >> 6);
    const int lane = threadIdx.x & 63;
    if (r >= rows) return;
    const float* srow;
    if constexpr (MODE == 0) {
        int b = r / kNT, rem = r - b * kNT, n = rem >> 3, t = rem & 7;
        srow = src + (((size_t)((b * 8 + t) * 196 + n)) << 10);
    } else {
        int s2 = r / kSeqS, i = r - s2 * kSeqS, b = s2 >> 3, t = s2 & 7;
        srow = (i == 0) ? (src2 + ((size_t)b << 10))
                        : (src + (((size_t)(b * kNT + ((i - 1) << 3) + t)) << 10));
    }
    float4 v[4]; float s = 0.f, ss = 0.f;
#pragma unroll
    for (int j = 0; j < 4; ++j) {
        v[j] = *(const float4*)&srow[((j << 6) + lane) << 2];
        s  += v[j].x + v[j].y + v[j].z + v[j].w;
        ss += v[j].x * v[j].x + v[j].y * v[j].y + v[j].z * v[j].z + v[j].w * v[j].w;
    }
#pragma unroll
    for (int off = 1; off < 64; off <<= 1) { s += __shfl_xor(s, off); ss += __shfl_xor(ss, off); }
    const float mean = s * (1.f / 1024.f);
    const float rstd = rsqrtf(ss * (1.f / 1024.f) - mean * mean + 1e-5f);
#pragma unroll
    for (int j = 0; j < 4; ++j) {
        const int c = ((j << 6) + lane) << 2;
        float4 gg = *(const float4*)&g[c];
        float4 bb = *(const float4*)&bt[c];
        ushort4 o;
        o.x = f2bf((v[j].x - mean) * rstd * gg.x + bb.x);
        o.y = f2bf((v[j].y - mean) * rstd * gg.y + bb.y);
        o.z = f2bf((v[j].z - mean) * rstd * gg.z + bb.z);
        o.w = f2bf((v[j].w - mean) * rstd * gg.w + bb.w);
        *(ushort4*)&out[((size_t)r << 10) + c] = o;
    }
}

// ---------------------------------------------------------------------------
// Fused build_x2 + LayerNorm(n2): one block per x2 row.
// Writes x2 (f32, fc2 residual) AND ln(x2) (bf16, fc1 input) in one pass.
// ---------------------------------------------------------------------------
__global__ void bx2ln_k(const float* __restrict__ xt, const float* __restrict__ xs,
                        const float* __restrict__ cls, const float* __restrict__ cm,
                        const float* __restrict__ g, const float* __restrict__ bt,
                        float* __restrict__ x2, u16* __restrict__ out) {
    __shared__ float red[2][4];
    const int r = blockIdx.x;
    const int tid = threadIdx.x, lane = tid & 63, wave = tid >> 6;
    const int c = tid << 2;
    const int b = r / 1569, i = r - b * 1569;
    const float* pa; const float* pb;
    if (i == 0) {
        pa = cls + ((size_t)b << 10) + c;
        pb = cm + ((size_t)b << 10) + c;
    } else {
        const int jj = i - 1, n = jj >> 3, t = jj & 7;
        pa = xt + (((size_t)(b * 1568 + jj)) << 10) + c;
        pb = xs + (((size_t)((b * 8 + t) * kSeqS + 1 + n)) << 10) + c;
    }
    const float4 va = *(const float4*)pa;
    const float4 vb = *(const float4*)pb;
    float4 vo;
    vo.x = va.x + vb.x; vo.y = va.y + vb.y; vo.z = va.z + vb.z; vo.w = va.w + vb.w;
    *(float4*)&x2[((size_t)r << 10) + c] = vo;
    float s  = vo.x + vo.y + vo.z + vo.w;
    float ss = vo.x * vo.x + vo.y * vo.y + vo.z * vo.z + vo.w * vo.w;
#pragma unroll
    for (int off = 1; off < 64; off <<= 1) { s += __shfl_xor(s, off); ss += __shfl_xor(ss, off); }
    if (lane == 0) { red[0][wave] = s; red[1][wave] = ss; }
    __syncthreads();
    s  = red[0][0] + red[0][1] + red[0][2] + red[0][3];
    ss = red[1][0] + red[1][1] + red[1][2] + red[1][3];
    const float mean = s * (1.f / 1024.f);
    const float rstd = rsqrtf(ss * (1.f / 1024.f) - mean * mean + 1e-5f);
    const float4 gg = *(const float4*)&g[c];
    const float4 bb = *(const float4*)&bt[c];
    ushort4 o;
    o.x = f2bf((vo.x - mean) * rstd * gg.x + bb.x);
    o.y = f2bf((vo.y - mean) * rstd * gg.y + bb.y);
    o.z = f2bf((vo.z - mean) * rstd * gg.z + bb.z);
    o.w = f2bf((vo.w - mean) * rstd * gg.w + bb.w);
    *(ushort4*)&out[((size_t)r << 10) + c] = o;
}

// ---------------------------------------------------------------------------
// GEMM: C[M,N] = A[M,K](bf16) @ W[N,K]^T(bf16) + bias, TMxTN tile, BK=32,
// 4 waves (2x2; wave tile (TM/2)x(TN/2)), 16x16x32 bf16 MFMA,
// global_load_lds staging, 2 barriers per K-step (R2 structure).
// LDS swizzle (R5, conflict-free): phys 16B slot s at row r holds logical
// k-sub j = s ^ ((r>>1)&3); XOR carried on the per-lane GLOBAL source
// (gll16 LDS dest stays linear); ds_read uses slot hi^((lo>>1)&3).
// XCD-chunked block swizzle, GENERAL bijective form (m204): works for any
// nwg (qkv_t grid 588 is not %8).
// TN=256 for wide-N GEMMs: wave tile 64x128 -> 12 b128 reads / 32 MFMAs
// (vs 8/16 at 64x64) -- attacks the measured LDS-read bound (R12).
// MODE 0: out bf16               MODE 1: out f32
// MODE 2: GELU(fast) -> bf16     MODE 3: + x-perm residual -> f32
// MODE 4: + x2 residual -> scatter to d_out (xo | cls_out), f32
// ---------------------------------------------------------------------------
template<int MODE, int TM, int TN>
__global__ void gemm_bt(
        const u16* __restrict__ A, const u16* __restrict__ W,
        const float* __restrict__ bias,
        u16* __restrict__ outB, float* __restrict__ outF,
        const float* __restrict__ resid, float* __restrict__ dout,
        int M, int N, int K) {
    constexpr int MF  = TM / 32;    // per-wave M fragments
    constexpr int NF  = TN / 32;    // per-wave N fragments
    constexpr int NCA = TM / 64;    // A staging chunks per lane
    constexpr int NCB = TN / 64;    // B staging chunks per lane
    __shared__ __align__(16) u16 As[TM * 32];
    __shared__ __align__(16) u16 Bs[TN * 32];
    const int tid  = threadIdx.x;
    const int lane = tid & 63, wave = tid >> 6;
    const int lo = lane & 15, hi = lane >> 4;
    const int wr = wave >> 1, wc = wave & 1;

    // XCD-chunked swizzle, bijective for any nwg (m204 general form)
    const int nbx = gridDim.x;
    const int nwg = nbx * gridDim.y;
    int bid = blockIdx.y * nbx + blockIdx.x;
    {
        const int q = nwg >> 3, r8 = nwg & 7, xcd = bid & 7, idx = bid >> 3;
        bid = (xcd < r8 ? xcd * (q + 1) : r8 * (q + 1) + (xcd - r8) * q) + idx;
    }
    const int row0 = (bid / nbx) * TM, col0 = (bid % nbx) * TN;

    // staging: chunk c (16B) -> LDS row c>>2, phys slot c&3; logical k-sub
    // j = (c&3) ^ ((row>>1)&3) carried on the global source address.
    const u16* aP[NCA]; const u16* bP[NCB];
#pragma unroll
    for (int i = 0; i < NCA; ++i) {
        const int c = wave * TM + (i << 6) + lane;
        const int row = c >> 2;
        const int jl = (((c & 3) ^ ((c >> 3) & 3)) << 3);
        int ar = row0 + row; if (ar > M - 1) ar = M - 1;
        aP[i] = A + (size_t)ar * K + jl;
    }
#pragma unroll
    for (int i = 0; i < NCB; ++i) {
        const int c = wave * TN + (i << 6) + lane;
        const int row = c >> 2;
        const int jl = (((c & 3) ^ ((c >> 3) & 3)) << 3);
        int br = col0 + row; if (br > N - 1) br = N - 1;
        bP[i] = W + (size_t)br * K + jl;
    }

    f32x4 acc[MF][NF] = {};
    const int sl = (hi ^ ((lo >> 1) & 3)) << 3;   // swizzled 16B read slot

    for (int k0 = 0; k0 < K; k0 += 32) {
#pragma unroll
        for (int i = 0; i < NCA; ++i)
            gll16(aP[i] + k0, &As[wave * (TM * 8) + (i << 9)]);
#pragma unroll
        for (int i = 0; i < NCB; ++i)
            gll16(bP[i] + k0, &Bs[wave * (TN * 8) + (i << 9)]);
        __syncthreads();   // implicit vmcnt(0): tile ready
        bf16x8 af[MF], bfr[NF];
#pragma unroll
        for (int m = 0; m < MF; ++m)
            af[m] = *(const bf16x8*)&As[((wr * (TM / 2) + (m << 4) + lo) << 5) + sl];
#pragma unroll
        for (int n = 0; n < NF; ++n)
            bfr[n] = *(const bf16x8*)&Bs[((wc * (TN / 2) + (n << 4) + lo) << 5) + sl];
#pragma unroll
        for (int m = 0; m < MF; ++m)
#pragma unroll
            for (int n = 0; n < NF; ++n)
                acc[m][n] = __builtin_amdgcn_mfma_f32_16x16x32_bf16(af[m], bfr[n], acc[m][n], 0, 0, 0);
        __syncthreads();   // protect LDS before next stage
    }

#pragma unroll
    for (int m = 0; m < MF; ++m) {
        const int rb = row0 + wr * (TM / 2) + (m << 4) + (hi << 2);
#pragma unroll
        for (int n = 0; n < NF; ++n) {
            const int c = col0 + wc * (TN / 2) + (n << 4) + lo;
            const float bc = bias[c];
#pragma unroll
            for (int j = 0; j < 4; ++j) {
                const int r = rb + j;
                if (r >= M) continue;
                float v = acc[m][n][j] + bc;
                if constexpr (MODE == 2) v = gelu_fast(v);
                if constexpr (MODE == 3) {
                    int b = r / 1568, rem = r - b * 1568, nn = rem >> 3, tt = rem & 7;
                    v += resid[(((size_t)((b * 8 + tt) * 196 + nn)) << 10) + c];
                }
                if constexpr (MODE == 0 || MODE == 2) {
                    outB[(size_t)r * N + c] = f2bf(v);
                } else if constexpr (MODE == 1 || MODE == 3) {
                    outF[(size_t)r * N + c] = v;
                } else {  // MODE 4
                    v += resid[((size_t)r << 10) + c];
                    int b = r / 1569, i = r - b * 1569;
                    if (i == 0) dout[kXO + ((size_t)b << 10) + c] = v;
                    else {
                        int jj = i - 1, nn = jj >> 3, tt = jj & 7;
                        dout[(((size_t)((b * 8 + tt) * 196 + nn)) << 10) + c] = v;
                    }
                }
            }
        }
    }
}

// ---------------------------------------------------------------------------
// Temporal attention: T=8, HD=64. One wave per (seq, head); 4 per block.
// R11: staging vectorized (3 bf16x8 loads/lane, part uniform per iteration).
// ---------------------------------------------------------------------------
__global__ void attn_a_k(const u16* __restrict__ qkv, u16* __restrict__ o) {
    __shared__ float lq[4][8][65], lk[4][8][65], lv[4][8][65];
    __shared__ float al[4][64];
    const int lane = threadIdx.x & 63, wave = threadIdx.x >> 6;
    const int p = (blockIdx.x << 2) + wave;   // 0..12543
    const int s = p >> 4, h = p & 15;
    const u16* base = qkv + (size_t)s * 24576 + (h << 6);
#pragma unroll
    for (int k = 0; k < 3; ++k) {
        const int t = lane >> 3, d8 = (lane & 7) << 3;
        union { bf16x8 v; u16 e[8]; } pk;
        pk.v = *(const bf16x8*)&base[(size_t)t * 3072 + (k << 10) + d8];
        float* dst = (k == 0) ? &lq[wave][t][d8] : (k == 1) ? &lk[wave][t][d8] : &lv[wave][t][d8];
#pragma unroll
        for (int z = 0; z < 8; ++z) dst[z] = bf2f(pk.e[z]);
    }
    __syncthreads();
    const int qi = lane >> 3, kj = lane & 7;
    float dot = 0.f;
#pragma unroll
    for (int d = 0; d < 64; ++d) dot += lq[wave][qi][d] * lk[wave][kj][d];
    dot *= SCALE;
    float m = dot;
    m = fmaxf(m, __shfl_xor(m, 1));
    m = fmaxf(m, __shfl_xor(m, 2));
    m = fmaxf(m, __shfl_xor(m, 4));
    const float e = expf(dot - m);
    float sm = e;
    sm += __shfl_xor(sm, 1);
    sm += __shfl_xor(sm, 2);
    sm += __shfl_xor(sm, 4);
    al[wave][lane] = e / sm;
    __syncthreads();
    u16* orow = o + (size_t)s * 8192 + (h << 6) + lane;
#pragma unroll
    for (int ii = 0; ii < 8; ++ii) {
        float accv = 0.f;
#pragma unroll
        for (int jj = 0; jj < 8; ++jj) accv += al[wave][(ii << 3) + jj] * lv[wave][jj][lane];
        orow[(size_t)ii * 1024] = f2bf(accv);
    }
}

// ---------------------------------------------------------------------------
// Spatial attention (MFMA flash-style): seq 197, HD=64.
// One block (4 waves) per (s2, head); waves own independent 16-row q-tiles;
// NO barriers in the main loop. See R2-R10 history.
// LDS: 64*232 + 4*16*232 u16 = 59,392 B  (2 blocks/CU).
// ---------------------------------------------------------------------------
__global__ __launch_bounds__(256, 2) void attn_s_mfma(const u16* __restrict__ qkv,
                                                      u16* __restrict__ o) {
    __shared__ __align__(16) u16 SM[29696];  // Vt[64][232] | P: 4 x [16][232]
    u16* __restrict__ Vt = SM;
    const int tid = threadIdx.x, lane = tid & 63, wave = tid >> 6;
    const int lo = lane & 15, hi = lane >> 4;
    u16* __restrict__ Pw = SM + 14848 + wave * 3712;
    const int s2 = blockIdx.x >> 4, h = blockIdx.x & 15;
    const u16* __restrict__ base = qkv + (size_t)s2 * (kSeqS * 3072) + (h << 6);

    // ---- stage V^T: Vt[d][k], k rows clamped at 196 (finite pad; P=0 there)
    for (int u = tid; u < 26 * 64; u += 256) {
        const int d = u & 63, k0 = (u >> 6) << 3;
        union { bf16x8 v; u16 e[8]; } pk;
#pragma unroll
        for (int i = 0; i < 8; ++i) {
            int kr = k0 + i; if (kr > 196) kr = 196;
            pk.e[i] = base[(size_t)kr * 3072 + 2048 + d];
        }
        *(bf16x8*)&Vt[d * 232 + k0] = pk.v;
    }
    // zero Vt cols 208..223 (PV kc=6 reads up to col 223; must be finite)
    for (int u = tid; u < 1024; u += 256)
        Vt[(u >> 4) * 232 + 208 + (u & 15)] = 0;
    // zero P cols 208..223 (written once; softmax rewrites only cols 0..207)
    for (int u = lane; u < 256; u += 64)
        Pw[(u >> 4) * 232 + 208 + (u & 15)] = 0;
    __syncthreads();

    for (int qt = wave; qt < 13; qt += 4) {
        int qr = qt * 16 + lo; if (qr > 196) qr = 196;
        const u16* qp = base + (size_t)qr * 3072;
        const bf16x8 aq0 = *(const bf16x8*)&qp[hi << 3];
        const bf16x8 aq1 = *(const bf16x8*)&qp[32 + (hi << 3)];

        // ---- S = Q K^T (scaled), 13 k-tiles x K=64
        f32x4 s[13];
#pragma unroll
        for (int kt = 0; kt < 13; ++kt) {
            int kr = kt * 16 + lo; if (kr > 196) kr = 196;
            const u16* kp = base + (size_t)kr * 3072 + 1024;
            const bf16x8 bk0 = *(const bf16x8*)&kp[hi << 3];
            const bf16x8 bk1 = *(const bf16x8*)&kp[32 + (hi << 3)];
            f32x4 acc = {};
            acc = __builtin_amdgcn_mfma_f32_16x16x32_bf16(aq0, bk0, acc, 0, 0, 0);
            acc = __builtin_amdgcn_mfma_f32_16x16x32_bf16(aq1, bk1, acc, 0, 0, 0);
            s[kt] = acc * SCALE;
        }
        if (lo > 4) s[12] = (f32x4){-1e30f, -1e30f, -1e30f, -1e30f};  // mask k>=197

        // ---- softmax over k (per output row hi*4+j)
        float inv[4];
#pragma unroll
        for (int j = 0; j < 4; ++j) {
            float m = s[0][j];
#pragma unroll
            for (int kt = 1; kt < 13; ++kt) m = fmaxf(m, s[kt][j]);
            m = fmaxf(m, __shfl_xor(m, 1));
            m = fmaxf(m, __shfl_xor(m, 2));
            m = fmaxf(m, __shfl_xor(m, 4));
            m = fmaxf(m, __shfl_xor(m, 8));
            float sum = 0.f;
#pragma unroll
            for (int kt = 0; kt < 13; ++kt) {
                const float e = __expf(s[kt][j] - m);
                s[kt][j] = e;
                sum += e;
            }
            sum += __shfl_xor(sum, 1);
            sum += __shfl_xor(sum, 2);
            sum += __shfl_xor(sum, 4);
            sum += __shfl_xor(sum, 8);
            inv[j] = 1.f / sum;
        }

        // ---- P (unnormalized) -> per-wave LDS, bf16
#pragma unroll
        for (int kt = 0; kt < 13; ++kt)
#pragma unroll
            for (int j = 0; j < 4; ++j)
                Pw[((hi << 2) + j) * 232 + kt * 16 + lo] = f2bf(s[kt][j]);

        // ---- O = P V  (7 K=32 chunks; chunk 6 uses zero-padded P/V cols)
        f32x4 o4[4] = {};
#pragma unroll
        for (int kc = 0; kc < 7; ++kc) {
            const bf16x8 pa = *(const bf16x8*)&Pw[lo * 232 + kc * 32 + (hi << 3)];
#pragma unroll
            for (int dt = 0; dt < 4; ++dt) {
                const bf16x8 vf = *(const bf16x8*)&Vt[(dt * 16 + lo) * 232 + kc * 32 + (hi << 3)];
                o4[dt] = __builtin_amdgcn_mfma_f32_16x16x32_bf16(pa, vf, o4[dt], 0, 0, 0);
            }
        }

        // ---- write (apply 1/sum in f32 here)
#pragma unroll
        for (int j = 0; j < 4; ++j) {
            const int q = qt * 16 + (hi << 2) + j;
            if (q > 196) continue;
            u16* orow = o + (((size_t)(s2 * kSeqS + q)) << 10) + (h << 6);
#pragma unroll
            for (int dt = 0; dt < 4; ++dt)
                orow[dt * 16 + lo] = f2bf(o4[dt][j] * inv[j]);
        }
    }
}

// cls_m[b][c] = mean over t of xs[(b*8+t)*197 + 0][c]
__global__ void clsm_k(const float* __restrict__ xs, float* __restrict__ cm) {
    const int idx = blockIdx.x * 256 + threadIdx.x;
    if (idx >= 4096) return;
    const int b = idx >> 10, c = idx & 1023;
    float s = 0.f;
#pragma unroll
    for (int t = 0; t < 8; ++t) s += xs[(((size_t)(b * 8 + t)) * kSeqS) * 1024 + c];
    cm[idx] = s * 0.125f;
}

// ---------------------------------------------------------------------------
extern "C" void kernel_launch(void* const* d_in, const int* in_sizes, int n_in,
                              void* d_out, int out_size, void* d_ws, size_t ws_size,
                              hipStream_t stream) {
    const float* x       = (const float*)d_in[0];
    const float* cls     = (const float*)d_in[1];
    const float* tln_g   = (const float*)d_in[2];
    const float* tln_b   = (const float*)d_in[3];
    const float* t_wqkv  = (const float*)d_in[4];
    const float* t_qb    = (const float*)d_in[5];
    const float* t_vb    = (const float*)d_in[6];
    const float* t_wproj = (const float*)d_in[7];
    const float* t_bproj = (const float*)d_in[8];
    const float* t_fc_w  = (const float*)d_in[9];
    const float* t_fc_b  = (const float*)d_in[10];
    const float* n1_g    = (const float*)d_in[11];
    const float* n1_b    = (const float*)d_in[12];
    const float* s_wqkv  = (const float*)d_in[13];
    const float* s_qb    = (const float*)d_in[14];
    const float* s_vb    = (const float*)d_in[15];
    const float* s_wproj = (const float*)d_in[16];
    const float* s_bproj = (const float*)d_in[17];
    const float* n2_g    = (const float*)d_in[18];
    const float* n2_b    = (const float*)d_in[19];
    const float* fc1_w   = (const float*)d_in[20];
    const float* fc1_b   = (const float*)d_in[21];
    const float* fc2_w   = (const float*)d_in[22];
    const float* fc2_b   = (const float*)d_in[23];
    float* dout = (float*)d_out;
    char* ws = (char*)d_ws;

    size_t off = 0;
    auto alloc = [&](size_t bytes) { size_t o = off; off += (bytes + 255) & ~(size_t)255; return o; };

    u16* t_wqkv_bf  = (u16*)(ws + alloc(3145728ull * 2));
    u16* wpT_bf     = (u16*)(ws + alloc(1048576ull * 2));   // wp^T (for Wcomb prep)
    u16* t_fcw_bf   = (u16*)(ws + alloc(1048576ull * 2));
    u16* s_wqkv_bf  = (u16*)(ws + alloc(3145728ull * 2));
    u16* s_wproj_bf = (u16*)(ws + alloc(1048576ull * 2));
    u16* fc1_bf     = (u16*)(ws + alloc(4194304ull * 2));
    u16* fc2_bf     = (u16*)(ws + alloc(4194304ull * 2));
    u16* ln_bf      = (u16*)(ws + alloc((size_t)kRowsS * 1024 * 2));
    u16* qkv_bf     = (u16*)(ws + alloc((size_t)kRowsS * 3072 * 2));
    u16* o_bf       = (u16*)(ws + alloc((size_t)kRowsS * 1024 * 2));
    u16* h1_bf      = qkv_bf;  // fc1 out (6276*4096*2 B) aliases dead qkv+o regions
    u16* wcomb_bf   = (u16*)(ws + alloc(1048576ull * 2));   // Wfc·Wp, bf16 [out][k]
    float* xt_f     = (float*)(ws + alloc((size_t)kRowsA * 1024 * 4));
    float* xs_f     = (float*)(ws + alloc((size_t)kRowsS * 1024 * 4));
    float* x2_f     = (float*)(ws + alloc((size_t)kRowsC * 1024 * 4));
    float* bias_t   = (float*)(ws + alloc(3072 * 4));
    float* bias_s   = (float*)(ws + alloc(3072 * 4));
    float* clsm     = (float*)(ws + alloc(4096 * 4));
    float* bcomb    = (float*)(ws + alloc(1024 * 4));
    (void)ws_size; (void)in_sizes; (void)n_in; (void)out_size;

    // weights -> bf16: all six conversions in ONE launch (R11)
    ConvJobs6 jobs;
    jobs.j[0] = { t_wqkv, t_wqkv_bf, 786432 };
    jobs.j[1] = { t_fc_w, t_fcw_bf,  262144 };
    jobs.j[2] = { s_wqkv, s_wqkv_bf, 786432 };
    jobs.j[3] = { s_wproj, s_wproj_bf, 262144 };
    jobs.j[4] = { fc1_w, fc1_bf, 1048576 };
    jobs.j[5] = { fc2_w, fc2_bf, 1048576 };
    convw6_k<<<dim3(2048), dim3(256), 0, stream>>>(jobs);
    bias3x2_k<<<dim3(12), dim3(256), 0, stream>>>(t_qb, t_vb, s_qb, s_vb, bias_t, bias_s);
    transpose_bf_k<<<dim3(64, 64), dim3(256), 0, stream>>>(t_wproj, wpT_bf);
    bcomb_k<<<dim3(256), dim3(256), 0, stream>>>(t_fc_w, t_bproj, t_fc_b, bcomb);
    // Wcomb[o][k] = sum_j fc_w[o][j] * wp[j][k]  (A=fc_w, W=wp^T; zero bias)
    gemm_bt<0, 128, 128><<<dim3(8, 8), dim3(256), 0, stream>>>(
        t_fcw_bf, wpT_bf, bias_t + 1024, wcomb_bf, nullptr, nullptr, nullptr, 1024, 1024, 1024);

    // ---- temporal branch ----
    ln_k<0><<<dim3(kRowsA / 4), dim3(256), 0, stream>>>(x, nullptr, tln_g, tln_b, ln_bf, kRowsA);
    gemm_bt<0, 128, 256><<<dim3(12, 49), dim3(256), 0, stream>>>(ln_bf, t_wqkv_bf, bias_t, qkv_bf, nullptr, nullptr, nullptr, kRowsA, 3072, 1024);
    attn_a_k<<<dim3(3136), dim3(256), 0, stream>>>(qkv_bf, o_bf);
    // fused proj+fc: xt = o @ Wcomb^T + bcomb + x_perm
    gemm_bt<3, 64, 128><<<dim3(8, 98), dim3(256), 0, stream>>>(o_bf, wcomb_bf, bcomb, nullptr, xt_f, x, nullptr, kRowsA, 1024, 1024);

    // ---- spatial branch ----
    ln_k<1><<<dim3(kRowsS / 4), dim3(256), 0, stream>>>(xt_f, cls, n1_g, n1_b, ln_bf, kRowsS);
    gemm_bt<0, 128, 256><<<dim3(12, 50), dim3(256), 0, stream>>>(ln_bf, s_wqkv_bf, bias_s, qkv_bf, nullptr, nullptr, nullptr, kRowsS, 3072, 1024);
    attn_s_mfma<<<dim3(512), dim3(256), 0, stream>>>(qkv_bf, o_bf);
    gemm_bt<1, 64, 128><<<dim3(8, 99), dim3(256), 0, stream>>>(o_bf, s_wproj_bf, s_bproj, nullptr, xs_f, nullptr, nullptr, kRowsS, 1024, 1024);
    clsm_k<<<dim3(16), dim3(256), 0, stream>>>(xs_f, clsm);
    // fused build_x2 + ln(n2): writes x2_f (f32) and ln_bf (bf16) in one pass
    bx2ln_k<<<dim3(kRowsC), dim3(256), 0, stream>>>(xt_f, xs_f, cls, clsm, n2_g, n2_b, x2_f, ln_bf);

    // ---- MLP ----
    // fc1: 128x256 tile (wave 64x128) + fast GELU
    gemm_bt<2, 128, 256><<<dim3(16, 50), dim3(256), 0, stream>>>(ln_bf, fc1_bf, fc1_b, h1_bf, nullptr, nullptr, nullptr, kRowsC, 4096, 1024);
    // fc2: TM=64 -> 792 blocks (3.1/CU)
    gemm_bt<4, 64, 128><<<dim3(8, 99), dim3(256), 0, stream>>>(h1_bf, fc2_bf, fc2_b, nullptr, nullptr, x2_f, dout, kRowsC, 1024, 4096);
}

// Round 13
// 518.162 us; speedup vs baseline: 3.2839x; 3.2839x over previous
//
#include <hip/hip_runtime.h>
#include <stdint.h>

// ---------------------------------------------------------------------------
// Block_44074954391877: ViT mixed block (temporal attn + spatial attn + MLP)
// B=4, T=8, N=196, C=1024, HEADS=16, HD=64, HIDDEN=4096
// Strategy: bf16 MFMA (16x16x32) for all GEMMs AND spatial attention, f32
// accumulate. GEMM = R2 structure (2-barrier, BK=32) + conflict-free LDS
// swizzle (R5) + bijective XCD-chunked block swizzle (m204 general form).
// R12 lesson (spill): without __launch_bounds__, hipcc targets 8 waves/SIMD
// -> 64-VGPR cap -> the TN=256 kernel's 128-reg accumulator spilled to
// scratch (VGPR_Count=64, 2.5GB traffic, MfmaUtil 3.5%). R13 fix:
// __launch_bounds__(256, 2) for TN>=256 -> 256-VGPR budget, 2 blocks/CU.
// R12 theory (still live): GEMMs are LDS-READ-BOUND (8 b128 = 384 cyc vs
// 77 cyc MFMA -> ~20% MfmaUtil); TN=256 wave tile 64x128 cuts LDS
// bytes/FLOP by 25%.
// TILE POLICY: TM=64/TN=128 ONLY for grid-starved N=1024 GEMMs.
// GELU fast (R9). Wcomb fusion (R6). bx2+ln fused (R8). Prep fused (R11).
// ---------------------------------------------------------------------------

#define SCALE 0.125f

typedef unsigned short u16;
typedef short bf16x8 __attribute__((ext_vector_type(8)));
typedef float f32x4 __attribute__((ext_vector_type(4)));

static constexpr int kNT    = 1568;     // N*T
static constexpr int kRowsA = 6272;     // B*N*T (temporal rows)
static constexpr int kSeqS  = 197;      // N+1 (spatial seq len)
static constexpr int kRowsS = 6304;     // B*T*197
static constexpr int kRowsC = 6276;     // B*1569 (x2 rows)
static constexpr size_t kXO = 6422528;  // elements of xo output

__device__ __forceinline__ float bf2f(u16 u) {
    union { unsigned int i; float f; } c; c.i = ((unsigned int)u) << 16; return c.f;
}
__device__ __forceinline__ u16 f2bf(float f) {
    union { float f; unsigned int i; } c; c.f = f;
    unsigned int r = c.i + 0x7FFFu + ((c.i >> 16) & 1u);  // RNE
    return (u16)(r >> 16);
}

// async global->LDS, 16B per lane; dst must be wave-uniform base (HW adds lane*16)
__device__ __forceinline__ void gll16(const void* g, void* l) {
    __builtin_amdgcn_global_load_lds((__attribute__((address_space(1))) void*)g,
                                     (__attribute__((address_space(3))) void*)l,
                                     16, 0, 0);
}

// fast GELU (tanh form): v*e/(1+e), e = exp(2z), z = v*(0.79788456+0.03567741*v*v)
__device__ __forceinline__ float gelu_fast(float v) {
    const float zz = 2.f * v * (0.79788456f + 0.03567741f * v * v);
    const float e = __expf(fminf(zz, 40.f));
    return v * e / (1.f + e);
}

// ---------------------------------------------------------------------------
// Fused f32 -> bf16 weight conversion: 6 jobs in ONE launch (R11).
// ---------------------------------------------------------------------------
struct ConvJob { const float* src; u16* dst; int n4; };
struct ConvJobs6 { ConvJob j[6]; };

__global__ void convw6_k(ConvJobs6 jobs) {
    const int stride = gridDim.x * blockDim.x;
    const int t0 = blockIdx.x * blockDim.x + threadIdx.x;
#pragma unroll
    for (int k = 0; k < 6; ++k) {
        const float* __restrict__ in = jobs.j[k].src;
        u16* __restrict__ out = jobs.j[k].dst;
        const int n4 = jobs.j[k].n4;
        for (int i = t0; i < n4; i += stride) {
            float4 v = ((const float4*)in)[i];
            ushort4 o;
            o.x = f2bf(v.x); o.y = f2bf(v.y); o.z = f2bf(v.z); o.w = f2bf(v.w);
            ((ushort4*)out)[i] = o;
        }
    }
}

// 1024x1024 f32 -> bf16 TRANSPOSE (out[k][j] = in[j][k]) for Wcomb prep
__global__ void transpose_bf_k(const float* __restrict__ in, u16* __restrict__ out) {
    __shared__ float t[16][17];
    const int tx = threadIdx.x & 15, ty = threadIdx.x >> 4;
    const int bx = blockIdx.x, by = blockIdx.y;
    t[ty][tx] = in[(size_t)(by * 16 + ty) * 1024 + bx * 16 + tx];
    __syncthreads();
    out[(size_t)(bx * 16 + ty) * 1024 + by * 16 + tx] = f2bf(t[tx][ty]);
}

// bcomb[o] = sum_j fcw[o][j]*bp[j] + fcb[o]  (f32; one wave per row)
__global__ void bcomb_k(const float* __restrict__ fcw, const float* __restrict__ bp,
                        const float* __restrict__ fcb, float* __restrict__ out) {
    const int row = blockIdx.x * 4 + (threadIdx.x >> 6);
    const int lane = threadIdx.x & 63;
    float s = 0.f;
#pragma unroll
    for (int i = 0; i < 16; ++i)
        s += fcw[(size_t)row * 1024 + (i << 6) + lane] * bp[(i << 6) + lane];
#pragma unroll
    for (int off = 1; off < 64; off <<= 1) s += __shfl_xor(s, off);
    if (lane == 0) out[row] = s + fcb[row];
}

// both bias3072 vectors in one launch: [qb | zeros | vb] for temporal+spatial
__global__ void bias3x2_k(const float* __restrict__ qbt, const float* __restrict__ vbt,
                          const float* __restrict__ qbs, const float* __restrict__ vbs,
                          float* __restrict__ dt, float* __restrict__ ds) {
    const int i = blockIdx.x * 256 + threadIdx.x;
    if (i >= 3072) return;
    dt[i] = (i < 1024) ? qbt[i] : (i < 2048) ? 0.0f : vbt[i - 2048];
    ds[i] = (i < 1024) ? qbs[i] : (i < 2048) ? 0.0f : vbs[i - 2048];
}

// ---------------------------------------------------------------------------
// LayerNorm (one wave per row of 1024), gathers per stage, writes bf16.
// MODE 0: temporal (src=x, row r=b*1568+n*8+t  <- x[b][t][n][:])
// MODE 1: spatial  (src=xt_f, src2=cls_token; r=s2*197+i)
// ---------------------------------------------------------------------------
template<int MODE>
__global__ void ln_k(const float* __restrict__ src, const float* __restrict__ src2,
                     const float* __restrict__ g, const float* __restrict__ bt,
                     u16* __restrict__ out, int rows) {
    const int r = (blockIdx.x << 2) + (threadIdx.x >> 6);
    const int lane = threadIdx.x & 63;
    if (r >= rows) return;
    const float* srow;
    if constexpr (MODE == 0) {
        int b = r / kNT, rem = r - b * kNT, n = rem >> 3, t = rem & 7;
        srow = src + (((size_t)((b * 8 + t) * 196 + n)) << 10);
    } else {
        int s2 = r / kSeqS, i = r - s2 * kSeqS, b = s2 >> 3, t = s2 & 7;
        srow = (i == 0) ? (src2 + ((size_t)b << 10))
                        : (src + (((size_t)(b * kNT + ((i - 1) << 3) + t)) << 10));
    }
    float4 v[4]; float s = 0.f, ss = 0.f;
#pragma unroll
    for (int j = 0; j < 4; ++j) {
        v[j] = *(const float4*)&srow[((j << 6) + lane) << 2];
        s  += v[j].x + v[j].y + v[j].z + v[j].w;
        ss += v[j].x * v[j].x + v[j].y * v[j].y + v[j].z * v[j].z + v[j].w * v[j].w;
    }
#pragma unroll
    for (int off = 1; off < 64; off <<= 1) { s += __shfl_xor(s, off); ss += __shfl_xor(ss, off); }
    const float mean = s * (1.f / 1024.f);
    const float rstd = rsqrtf(ss * (1.f / 1024.f) - mean * mean + 1e-5f);
#pragma unroll
    for (int j = 0; j < 4; ++j) {
        const int c = ((j << 6) + lane) << 2;
        float4 gg = *(const float4*)&g[c];
        float4 bb = *(const float4*)&bt[c];
        ushort4 o;
        o.x = f2bf((v[j].x - mean) * rstd * gg.x + bb.x);
        o.y = f2bf((v[j].y - mean) * rstd * gg.y + bb.y);
        o.z = f2bf((v[j].z - mean) * rstd * gg.z + bb.z);
        o.w = f2bf((v[j].w - mean) * rstd * gg.w + bb.w);
        *(ushort4*)&out[((size_t)r << 10) + c] = o;
    }
}

// ---------------------------------------------------------------------------
// Fused build_x2 + LayerNorm(n2): one block per x2 row.
// Writes x2 (f32, fc2 residual) AND ln(x2) (bf16, fc1 input) in one pass.
// ---------------------------------------------------------------------------
__global__ void bx2ln_k(const float* __restrict__ xt, const float* __restrict__ xs,
                        const float* __restrict__ cls, const float* __restrict__ cm,
                        const float* __restrict__ g, const float* __restrict__ bt,
                        float* __restrict__ x2, u16* __restrict__ out) {
    __shared__ float red[2][4];
    const int r = blockIdx.x;
    const int tid = threadIdx.x, lane = tid & 63, wave = tid >> 6;
    const int c = tid << 2;
    const int b = r / 1569, i = r - b * 1569;
    const float* pa; const float* pb;
    if (i == 0) {
        pa = cls + ((size_t)b << 10) + c;
        pb = cm + ((size_t)b << 10) + c;
    } else {
        const int jj = i - 1, n = jj >> 3, t = jj & 7;
        pa = xt + (((size_t)(b * 1568 + jj)) << 10) + c;
        pb = xs + (((size_t)((b * 8 + t) * kSeqS + 1 + n)) << 10) + c;
    }
    const float4 va = *(const float4*)pa;
    const float4 vb = *(const float4*)pb;
    float4 vo;
    vo.x = va.x + vb.x; vo.y = va.y + vb.y; vo.z = va.z + vb.z; vo.w = va.w + vb.w;
    *(float4*)&x2[((size_t)r << 10) + c] = vo;
    float s  = vo.x + vo.y + vo.z + vo.w;
    float ss = vo.x * vo.x + vo.y * vo.y + vo.z * vo.z + vo.w * vo.w;
#pragma unroll
    for (int off = 1; off < 64; off <<= 1) { s += __shfl_xor(s, off); ss += __shfl_xor(ss, off); }
    if (lane == 0) { red[0][wave] = s; red[1][wave] = ss; }
    __syncthreads();
    s  = red[0][0] + red[0][1] + red[0][2] + red[0][3];
    ss = red[1][0] + red[1][1] + red[1][2] + red[1][3];
    const float mean = s * (1.f / 1024.f);
    const float rstd = rsqrtf(ss * (1.f / 1024.f) - mean * mean + 1e-5f);
    const float4 gg = *(const float4*)&g[c];
    const float4 bb = *(const float4*)&bt[c];
    ushort4 o;
    o.x = f2bf((vo.x - mean) * rstd * gg.x + bb.x);
    o.y = f2bf((vo.y - mean) * rstd * gg.y + bb.y);
    o.z = f2bf((vo.z - mean) * rstd * gg.z + bb.z);
    o.w = f2bf((vo.w - mean) * rstd * gg.w + bb.w);
    *(ushort4*)&out[((size_t)r << 10) + c] = o;
}

// ---------------------------------------------------------------------------
// GEMM: C[M,N] = A[M,K](bf16) @ W[N,K]^T(bf16) + bias, TMxTN tile, BK=32,
// 4 waves (2x2; wave tile (TM/2)x(TN/2)), 16x16x32 bf16 MFMA,
// global_load_lds staging, 2 barriers per K-step (R2 structure).
// __launch_bounds__: TN>=256 -> 2 waves/EU (256-VGPR budget; the 128-reg
// accumulator MUST NOT spill -- R12: default 8-wave target capped at 64
// VGPRs and spilled acc to scratch, 2.5GB traffic, 600us/dispatch).
// LDS swizzle (R5, conflict-free) + general bijective XCD swizzle (m204).
// MODE 0: out bf16               MODE 1: out f32
// MODE 2: GELU(fast) -> bf16     MODE 3: + x-perm residual -> f32
// MODE 4: + x2 residual -> scatter to d_out (xo | cls_out), f32
// ---------------------------------------------------------------------------
template<int MODE, int TM, int TN>
__global__ __launch_bounds__(256, (TN >= 256 ? 2 : 4)) void gemm_bt(
        const u16* __restrict__ A, const u16* __restrict__ W,
        const float* __restrict__ bias,
        u16* __restrict__ outB, float* __restrict__ outF,
        const float* __restrict__ resid, float* __restrict__ dout,
        int M, int N, int K) {
    constexpr int MF  = TM / 32;    // per-wave M fragments
    constexpr int NF  = TN / 32;    // per-wave N fragments
    constexpr int NCA = TM / 64;    // A staging chunks per lane
    constexpr int NCB = TN / 64;    // B staging chunks per lane
    __shared__ __align__(16) u16 As[TM * 32];
    __shared__ __align__(16) u16 Bs[TN * 32];
    const int tid  = threadIdx.x;
    const int lane = tid & 63, wave = tid >> 6;
    const int lo = lane & 15, hi = lane >> 4;
    const int wr = wave >> 1, wc = wave & 1;

    // XCD-chunked swizzle, bijective for any nwg (m204 general form)
    const int nbx = gridDim.x;
    const int nwg = nbx * gridDim.y;
    int bid = blockIdx.y * nbx + blockIdx.x;
    {
        const int q = nwg >> 3, r8 = nwg & 7, xcd = bid & 7, idx = bid >> 3;
        bid = (xcd < r8 ? xcd * (q + 1) : r8 * (q + 1) + (xcd - r8) * q) + idx;
    }
    const int row0 = (bid / nbx) * TM, col0 = (bid % nbx) * TN;

    // staging: chunk c (16B) -> LDS row c>>2, phys slot c&3; logical k-sub
    // j = (c&3) ^ ((row>>1)&3) carried on the global source address.
    const u16* aP[NCA]; const u16* bP[NCB];
#pragma unroll
    for (int i = 0; i < NCA; ++i) {
        const int c = wave * TM + (i << 6) + lane;
        const int row = c >> 2;
        const int jl = (((c & 3) ^ ((c >> 3) & 3)) << 3);
        int ar = row0 + row; if (ar > M - 1) ar = M - 1;
        aP[i] = A + (size_t)ar * K + jl;
    }
#pragma unroll
    for (int i = 0; i < NCB; ++i) {
        const int c = wave * TN + (i << 6) + lane;
        const int row = c >> 2;
        const int jl = (((c & 3) ^ ((c >> 3) & 3)) << 3);
        int br = col0 + row; if (br > N - 1) br = N - 1;
        bP[i] = W + (size_t)br * K + jl;
    }

    f32x4 acc[MF][NF] = {};
    const int sl = (hi ^ ((lo >> 1) & 3)) << 3;   // swizzled 16B read slot

    for (int k0 = 0; k0 < K; k0 += 32) {
#pragma unroll
        for (int i = 0; i < NCA; ++i)
            gll16(aP[i] + k0, &As[wave * (TM * 8) + (i << 9)]);
#pragma unroll
        for (int i = 0; i < NCB; ++i)
            gll16(bP[i] + k0, &Bs[wave * (TN * 8) + (i << 9)]);
        __syncthreads();   // implicit vmcnt(0): tile ready
        bf16x8 af[MF], bfr[NF];
#pragma unroll
        for (int m = 0; m < MF; ++m)
            af[m] = *(const bf16x8*)&As[((wr * (TM / 2) + (m << 4) + lo) << 5) + sl];
#pragma unroll
        for (int n = 0; n < NF; ++n)
            bfr[n] = *(const bf16x8*)&Bs[((wc * (TN / 2) + (n << 4) + lo) << 5) + sl];
#pragma unroll
        for (int m = 0; m < MF; ++m)
#pragma unroll
            for (int n = 0; n < NF; ++n)
                acc[m][n] = __builtin_amdgcn_mfma_f32_16x16x32_bf16(af[m], bfr[n], acc[m][n], 0, 0, 0);
        __syncthreads();   // protect LDS before next stage
    }

#pragma unroll
    for (int m = 0; m < MF; ++m) {
        const int rb = row0 + wr * (TM / 2) + (m << 4) + (hi << 2);
#pragma unroll
        for (int n = 0; n < NF; ++n) {
            const int c = col0 + wc * (TN / 2) + (n << 4) + lo;
            const float bc = bias[c];
#pragma unroll
            for (int j = 0; j < 4; ++j) {
                const int r = rb + j;
                if (r >= M) continue;
                float v = acc[m][n][j] + bc;
                if constexpr (MODE == 2) v = gelu_fast(v);
                if constexpr (MODE == 3) {
                    int b = r / 1568, rem = r - b * 1568, nn = rem >> 3, tt = rem & 7;
                    v += resid[(((size_t)((b * 8 + tt) * 196 + nn)) << 10) + c];
                }
                if constexpr (MODE == 0 || MODE == 2) {
                    outB[(size_t)r * N + c] = f2bf(v);
                } else if constexpr (MODE == 1 || MODE == 3) {
                    outF[(size_t)r * N + c] = v;
                } else {  // MODE 4
                    v += resid[((size_t)r << 10) + c];
                    int b = r / 1569, i = r - b * 1569;
                    if (i == 0) dout[kXO + ((size_t)b << 10) + c] = v;
                    else {
                        int jj = i - 1, nn = jj >> 3, tt = jj & 7;
                        dout[(((size_t)((b * 8 + tt) * 196 + nn)) << 10) + c] = v;
                    }
                }
            }
        }
    }
}

// ---------------------------------------------------------------------------
// Temporal attention: T=8, HD=64. One wave per (seq, head); 4 per block.
// R11: staging vectorized (3 bf16x8 loads/lane, part uniform per iteration).
// ---------------------------------------------------------------------------
__global__ void attn_a_k(const u16* __restrict__ qkv, u16* __restrict__ o) {
    __shared__ float lq[4][8][65], lk[4][8][65], lv[4][8][65];
    __shared__ float al[4][64];
    const int lane = threadIdx.x & 63, wave = threadIdx.x >> 6;
    const int p = (blockIdx.x << 2) + wave;   // 0..12543
    const int s = p >> 4, h = p & 15;
    const u16* base = qkv + (size_t)s * 24576 + (h << 6);
#pragma unroll
    for (int k = 0; k < 3; ++k) {
        const int t = lane >> 3, d8 = (lane & 7) << 3;
        union { bf16x8 v; u16 e[8]; } pk;
        pk.v = *(const bf16x8*)&base[(size_t)t * 3072 + (k << 10) + d8];
        float* dst = (k == 0) ? &lq[wave][t][d8] : (k == 1) ? &lk[wave][t][d8] : &lv[wave][t][d8];
#pragma unroll
        for (int z = 0; z < 8; ++z) dst[z] = bf2f(pk.e[z]);
    }
    __syncthreads();
    const int qi = lane >> 3, kj = lane & 7;
    float dot = 0.f;
#pragma unroll
    for (int d = 0; d < 64; ++d) dot += lq[wave][qi][d] * lk[wave][kj][d];
    dot *= SCALE;
    float m = dot;
    m = fmaxf(m, __shfl_xor(m, 1));
    m = fmaxf(m, __shfl_xor(m, 2));
    m = fmaxf(m, __shfl_xor(m, 4));
    const float e = expf(dot - m);
    float sm = e;
    sm += __shfl_xor(sm, 1);
    sm += __shfl_xor(sm, 2);
    sm += __shfl_xor(sm, 4);
    al[wave][lane] = e / sm;
    __syncthreads();
    u16* orow = o + (size_t)s * 8192 + (h << 6) + lane;
#pragma unroll
    for (int ii = 0; ii < 8; ++ii) {
        float accv = 0.f;
#pragma unroll
        for (int jj = 0; jj < 8; ++jj) accv += al[wave][(ii << 3) + jj] * lv[wave][jj][lane];
        orow[(size_t)ii * 1024] = f2bf(accv);
    }
}

// ---------------------------------------------------------------------------
// Spatial attention (MFMA flash-style): seq 197, HD=64.
// One block (4 waves) per (s2, head); waves own independent 16-row q-tiles;
// NO barriers in the main loop. See R2-R10 history.
// LDS: 64*232 + 4*16*232 u16 = 59,392 B  (2 blocks/CU).
// ---------------------------------------------------------------------------
__global__ __launch_bounds__(256, 2) void attn_s_mfma(const u16* __restrict__ qkv,
                                                      u16* __restrict__ o) {
    __shared__ __align__(16) u16 SM[29696];  // Vt[64][232] | P: 4 x [16][232]
    u16* __restrict__ Vt = SM;
    const int tid = threadIdx.x, lane = tid & 63, wave = tid >> 6;
    const int lo = lane & 15, hi = lane >> 4;
    u16* __restrict__ Pw = SM + 14848 + wave * 3712;
    const int s2 = blockIdx.x >> 4, h = blockIdx.x & 15;
    const u16* __restrict__ base = qkv + (size_t)s2 * (kSeqS * 3072) + (h << 6);

    // ---- stage V^T: Vt[d][k], k rows clamped at 196 (finite pad; P=0 there)
    for (int u = tid; u < 26 * 64; u += 256) {
        const int d = u & 63, k0 = (u >> 6) << 3;
        union { bf16x8 v; u16 e[8]; } pk;
#pragma unroll
        for (int i = 0; i < 8; ++i) {
            int kr = k0 + i; if (kr > 196) kr = 196;
            pk.e[i] = base[(size_t)kr * 3072 + 2048 + d];
        }
        *(bf16x8*)&Vt[d * 232 + k0] = pk.v;
    }
    // zero Vt cols 208..223 (PV kc=6 reads up to col 223; must be finite)
    for (int u = tid; u < 1024; u += 256)
        Vt[(u >> 4) * 232 + 208 + (u & 15)] = 0;
    // zero P cols 208..223 (written once; softmax rewrites only cols 0..207)
    for (int u = lane; u < 256; u += 64)
        Pw[(u >> 4) * 232 + 208 + (u & 15)] = 0;
    __syncthreads();

    for (int qt = wave; qt < 13; qt += 4) {
        int qr = qt * 16 + lo; if (qr > 196) qr = 196;
        const u16* qp = base + (size_t)qr * 3072;
        const bf16x8 aq0 = *(const bf16x8*)&qp[hi << 3];
        const bf16x8 aq1 = *(const bf16x8*)&qp[32 + (hi << 3)];

        // ---- S = Q K^T (scaled), 13 k-tiles x K=64
        f32x4 s[13];
#pragma unroll
        for (int kt = 0; kt < 13; ++kt) {
            int kr = kt * 16 + lo; if (kr > 196) kr = 196;
            const u16* kp = base + (size_t)kr * 3072 + 1024;
            const bf16x8 bk0 = *(const bf16x8*)&kp[hi << 3];
            const bf16x8 bk1 = *(const bf16x8*)&kp[32 + (hi << 3)];
            f32x4 acc = {};
            acc = __builtin_amdgcn_mfma_f32_16x16x32_bf16(aq0, bk0, acc, 0, 0, 0);
            acc = __builtin_amdgcn_mfma_f32_16x16x32_bf16(aq1, bk1, acc, 0, 0, 0);
            s[kt] = acc * SCALE;
        }
        if (lo > 4) s[12] = (f32x4){-1e30f, -1e30f, -1e30f, -1e30f};  // mask k>=197

        // ---- softmax over k (per output row hi*4+j)
        float inv[4];
#pragma unroll
        for (int j = 0; j < 4; ++j) {
            float m = s[0][j];
#pragma unroll
            for (int kt = 1; kt < 13; ++kt) m = fmaxf(m, s[kt][j]);
            m = fmaxf(m, __shfl_xor(m, 1));
            m = fmaxf(m, __shfl_xor(m, 2));
            m = fmaxf(m, __shfl_xor(m, 4));
            m = fmaxf(m, __shfl_xor(m, 8));
            float sum = 0.f;
#pragma unroll
            for (int kt = 0; kt < 13; ++kt) {
                const float e = __expf(s[kt][j] - m);
                s[kt][j] = e;
                sum += e;
            }
            sum += __shfl_xor(sum, 1);
            sum += __shfl_xor(sum, 2);
            sum += __shfl_xor(sum, 4);
            sum += __shfl_xor(sum, 8);
            inv[j] = 1.f / sum;
        }

        // ---- P (unnormalized) -> per-wave LDS, bf16
#pragma unroll
        for (int kt = 0; kt < 13; ++kt)
#pragma unroll
            for (int j = 0; j < 4; ++j)
                Pw[((hi << 2) + j) * 232 + kt * 16 + lo] = f2bf(s[kt][j]);

        // ---- O = P V  (7 K=32 chunks; chunk 6 uses zero-padded P/V cols)
        f32x4 o4[4] = {};
#pragma unroll
        for (int kc = 0; kc < 7; ++kc) {
            const bf16x8 pa = *(const bf16x8*)&Pw[lo * 232 + kc * 32 + (hi << 3)];
#pragma unroll
            for (int dt = 0; dt < 4; ++dt) {
                const bf16x8 vf = *(const bf16x8*)&Vt[(dt * 16 + lo) * 232 + kc * 32 + (hi << 3)];
                o4[dt] = __builtin_amdgcn_mfma_f32_16x16x32_bf16(pa, vf, o4[dt], 0, 0, 0);
            }
        }

        // ---- write (apply 1/sum in f32 here)
#pragma unroll
        for (int j = 0; j < 4; ++j) {
            const int q = qt * 16 + (hi << 2) + j;
            if (q > 196) continue;
            u16* orow = o + (((size_t)(s2 * kSeqS + q)) << 10) + (h << 6);
#pragma unroll
            for (int dt = 0; dt < 4; ++dt)
                orow[dt * 16 + lo] = f2bf(o4[dt][j] * inv[j]);
        }
    }
}

// cls_m[b][c] = mean over t of xs[(b*8+t)*197 + 0][c]
__global__ void clsm_k(const float* __restrict__ xs, float* __restrict__ cm) {
    const int idx = blockIdx.x * 256 + threadIdx.x;
    if (idx >= 4096) return;
    const int b = idx >> 10, c = idx & 1023;
    float s = 0.f;
#pragma unroll
    for (int t = 0; t < 8; ++t) s += xs[(((size_t)(b * 8 + t)) * kSeqS) * 1024 + c];
    cm[idx] = s * 0.125f;
}

// ---------------------------------------------------------------------------
extern "C" void kernel_launch(void* const* d_in, const int* in_sizes, int n_in,
                              void* d_out, int out_size, void* d_ws, size_t ws_size,
                              hipStream_t stream) {
    const float* x       = (const float*)d_in[0];
    const float* cls     = (const float*)d_in[1];
    const float* tln_g   = (const float*)d_in[2];
    const float* tln_b   = (const float*)d_in[3];
    const float* t_wqkv  = (const float*)d_in[4];
    const float* t_qb    = (const float*)d_in[5];
    const float* t_vb    = (const float*)d_in[6];
    const float* t_wproj = (const float*)d_in[7];
    const float* t_bproj = (const float*)d_in[8];
    const float* t_fc_w  = (const float*)d_in[9];
    const float* t_fc_b  = (const float*)d_in[10];
    const float* n1_g    = (const float*)d_in[11];
    const float* n1_b    = (const float*)d_in[12];
    const float* s_wqkv  = (const float*)d_in[13];
    const float* s_qb    = (const float*)d_in[14];
    const float* s_vb    = (const float*)d_in[15];
    const float* s_wproj = (const float*)d_in[16];
    const float* s_bproj = (const float*)d_in[17];
    const float* n2_g    = (const float*)d_in[18];
    const float* n2_b    = (const float*)d_in[19];
    const float* fc1_w   = (const float*)d_in[20];
    const float* fc1_b   = (const float*)d_in[21];
    const float* fc2_w   = (const float*)d_in[22];
    const float* fc2_b   = (const float*)d_in[23];
    float* dout = (float*)d_out;
    char* ws = (char*)d_ws;

    size_t off = 0;
    auto alloc = [&](size_t bytes) { size_t o = off; off += (bytes + 255) & ~(size_t)255; return o; };

    u16* t_wqkv_bf  = (u16*)(ws + alloc(3145728ull * 2));
    u16* wpT_bf     = (u16*)(ws + alloc(1048576ull * 2));   // wp^T (for Wcomb prep)
    u16* t_fcw_bf   = (u16*)(ws + alloc(1048576ull * 2));
    u16* s_wqkv_bf  = (u16*)(ws + alloc(3145728ull * 2));
    u16* s_wproj_bf = (u16*)(ws + alloc(1048576ull * 2));
    u16* fc1_bf     = (u16*)(ws + alloc(4194304ull * 2));
    u16* fc2_bf     = (u16*)(ws + alloc(4194304ull * 2));
    u16* ln_bf      = (u16*)(ws + alloc((size_t)kRowsS * 1024 * 2));
    u16* qkv_bf     = (u16*)(ws + alloc((size_t)kRowsS * 3072 * 2));
    u16* o_bf       = (u16*)(ws + alloc((size_t)kRowsS * 1024 * 2));
    u16* h1_bf      = qkv_bf;  // fc1 out (6276*4096*2 B) aliases dead qkv+o regions
    u16* wcomb_bf   = (u16*)(ws + alloc(1048576ull * 2));   // Wfc·Wp, bf16 [out][k]
    float* xt_f     = (float*)(ws + alloc((size_t)kRowsA * 1024 * 4));
    float* xs_f     = (float*)(ws + alloc((size_t)kRowsS * 1024 * 4));
    float* x2_f     = (float*)(ws + alloc((size_t)kRowsC * 1024 * 4));
    float* bias_t   = (float*)(ws + alloc(3072 * 4));
    float* bias_s   = (float*)(ws + alloc(3072 * 4));
    float* clsm     = (float*)(ws + alloc(4096 * 4));
    float* bcomb    = (float*)(ws + alloc(1024 * 4));
    (void)ws_size; (void)in_sizes; (void)n_in; (void)out_size;

    // weights -> bf16: all six conversions in ONE launch (R11)
    ConvJobs6 jobs;
    jobs.j[0] = { t_wqkv, t_wqkv_bf, 786432 };
    jobs.j[1] = { t_fc_w, t_fcw_bf,  262144 };
    jobs.j[2] = { s_wqkv, s_wqkv_bf, 786432 };
    jobs.j[3] = { s_wproj, s_wproj_bf, 262144 };
    jobs.j[4] = { fc1_w, fc1_bf, 1048576 };
    jobs.j[5] = { fc2_w, fc2_bf, 1048576 };
    convw6_k<<<dim3(2048), dim3(256), 0, stream>>>(jobs);
    bias3x2_k<<<dim3(12), dim3(256), 0, stream>>>(t_qb, t_vb, s_qb, s_vb, bias_t, bias_s);
    transpose_bf_k<<<dim3(64, 64), dim3(256), 0, stream>>>(t_wproj, wpT_bf);
    bcomb_k<<<dim3(256), dim3(256), 0, stream>>>(t_fc_w, t_bproj, t_fc_b, bcomb);
    // Wcomb[o][k] = sum_j fc_w[o][j] * wp[j][k]  (A=fc_w, W=wp^T; zero bias)
    gemm_bt<0, 128, 128><<<dim3(8, 8), dim3(256), 0, stream>>>(
        t_fcw_bf, wpT_bf, bias_t + 1024, wcomb_bf, nullptr, nullptr, nullptr, 1024, 1024, 1024);

    // ---- temporal branch ----
    ln_k<0><<<dim3(kRowsA / 4), dim3(256), 0, stream>>>(x, nullptr, tln_g, tln_b, ln_bf, kRowsA);
    gemm_bt<0, 128, 256><<<dim3(12, 49), dim3(256), 0, stream>>>(ln_bf, t_wqkv_bf, bias_t, qkv_bf, nullptr, nullptr, nullptr, kRowsA, 3072, 1024);
    attn_a_k<<<dim3(3136), dim3(256), 0, stream>>>(qkv_bf, o_bf);
    // fused proj+fc: xt = o @ Wcomb^T + bcomb + x_perm
    gemm_bt<3, 64, 128><<<dim3(8, 98), dim3(256), 0, stream>>>(o_bf, wcomb_bf, bcomb, nullptr, xt_f, x, nullptr, kRowsA, 1024, 1024);

    // ---- spatial branch ----
    ln_k<1><<<dim3(kRowsS / 4), dim3(256), 0, stream>>>(xt_f, cls, n1_g, n1_b, ln_bf, kRowsS);
    gemm_bt<0, 128, 256><<<dim3(12, 50), dim3(256), 0, stream>>>(ln_bf, s_wqkv_bf, bias_s, qkv_bf, nullptr, nullptr, nullptr, kRowsS, 3072, 1024);
    attn_s_mfma<<<dim3(512), dim3(256), 0, stream>>>(qkv_bf, o_bf);
    gemm_bt<1, 64, 128><<<dim3(8, 99), dim3(256), 0, stream>>>(o_bf, s_wproj_bf, s_bproj, nullptr, xs_f, nullptr, nullptr, kRowsS, 1024, 1024);
    clsm_k<<<dim3(16), dim3(256), 0, stream>>>(xs_f, clsm);
    // fused build_x2 + ln(n2): writes x2_f (f32) and ln_bf (bf16) in one pass
    bx2ln_k<<<dim3(kRowsC), dim3(256), 0, stream>>>(xt_f, xs_f, cls, clsm, n2_g, n2_b, x2_f, ln_bf);

    // ---- MLP ----
    // fc1: 128x256 tile (wave 64x128) + fast GELU
    gemm_bt<2, 128, 256><<<dim3(16, 50), dim3(256), 0, stream>>>(ln_bf, fc1_bf, fc1_b, h1_bf, nullptr, nullptr, nullptr, kRowsC, 4096, 1024);
    // fc2: TM=64 -> 792 blocks (3.1/CU)
    gemm_bt<4, 64, 128><<<dim3(8, 99), dim3(256), 0, stream>>>(h1_bf, fc2_bf, fc2_b, nullptr, nullptr, x2_f, dout, kRowsC, 1024, 4096);
}

// Round 14
// 466.214 us; speedup vs baseline: 3.6498x; 1.1114x over previous
//
#include <hip/hip_runtime.h>
#include <stdint.h>

// ---------------------------------------------------------------------------
// Block_44074954391877: ViT mixed block (temporal attn + spatial attn + MLP)
// B=4, T=8, N=196, C=1024, HEADS=16, HD=64, HIDDEN=4096
// Strategy: bf16 MFMA (16x16x32) for all GEMMs AND spatial attention, f32
// accumulate. GEMM = R2 structure (2-barrier, BK=32, 16/12KB LDS) + verified
// conflict-free LDS swizzle (R5) + XCD-chunked block swizzle (R7).
// == R14: exact revert to R11 (best measured, 468us). ==
// PLATEAU RECORD (do not retry):
//  - R12: TN=256 w/o launch_bounds -> acc spilled (64-VGPR cap), 1702us.
//  - R13: TN=256 + launch_bounds(256,2) -> spill fixed but 2 blocks/CU;
//    fc1 110us > 86.5us, MfmaUtil 25->19. LDS-intensity theory REFUTED:
//    the ~600TF plateau is the occupancy x LDS-throughput product; both
//    knobs (bigger wave-tile/fewer waves, smaller tile/more waves) lose.
//  - R9: fc1@TM=64 doubled W stream -> HBM-bound, 114us. REVERTED.
//  - R5: counted-vmcnt 3-buf: conflicts->0 (swizzle verified) but 48KB LDS
//    cut occupancy; no win. R3/R4 dbuf variants: flat.
//  Next structural step would be the 8-wave 256^2 deep pipeline (T3+T4+T5),
//  a full rewrite -- high risk, not attempted headlessly.
// TILE POLICY: TM=64 ONLY for grid-starved N=1024 GEMMs (fused-temporal,
// s_proj, fc2 -- R8/R10); fc1/qkv stay TM=128.
// GELU = tanh-form fast approx (R9). Wcomb = Wfc*Wp fusion (R6).
// build_x2+ln2 fused (R8). Prep fused + attn_a vectorized (R11).
// ---------------------------------------------------------------------------

#define SCALE 0.125f

typedef unsigned short u16;
typedef short bf16x8 __attribute__((ext_vector_type(8)));
typedef float f32x4 __attribute__((ext_vector_type(4)));

static constexpr int kNT    = 1568;     // N*T
static constexpr int kRowsA = 6272;     // B*N*T (temporal rows)
static constexpr int kSeqS  = 197;      // N+1 (spatial seq len)
static constexpr int kRowsS = 6304;     // B*T*197
static constexpr int kRowsC = 6276;     // B*1569 (x2 rows)
static constexpr size_t kXO = 6422528;  // elements of xo output

__device__ __forceinline__ float bf2f(u16 u) {
    union { unsigned int i; float f; } c; c.i = ((unsigned int)u) << 16; return c.f;
}
__device__ __forceinline__ u16 f2bf(float f) {
    union { float f; unsigned int i; } c; c.f = f;
    unsigned int r = c.i + 0x7FFFu + ((c.i >> 16) & 1u);  // RNE
    return (u16)(r >> 16);
}

// async global->LDS, 16B per lane; dst must be wave-uniform base (HW adds lane*16)
__device__ __forceinline__ void gll16(const void* g, void* l) {
    __builtin_amdgcn_global_load_lds((__attribute__((address_space(1))) void*)g,
                                     (__attribute__((address_space(3))) void*)l,
                                     16, 0, 0);
}

// fast GELU (tanh form): v*e/(1+e), e = exp(2z), z = v*(0.79788456+0.03567741*v*v)
__device__ __forceinline__ float gelu_fast(float v) {
    const float zz = 2.f * v * (0.79788456f + 0.03567741f * v * v);
    const float e = __expf(fminf(zz, 40.f));
    return v * e / (1.f + e);
}

// ---------------------------------------------------------------------------
// Fused f32 -> bf16 weight conversion: 6 jobs in ONE launch (R11).
// ---------------------------------------------------------------------------
struct ConvJob { const float* src; u16* dst; int n4; };
struct ConvJobs6 { ConvJob j[6]; };

__global__ void convw6_k(ConvJobs6 jobs) {
    const int stride = gridDim.x * blockDim.x;
    const int t0 = blockIdx.x * blockDim.x + threadIdx.x;
#pragma unroll
    for (int k = 0; k < 6; ++k) {
        const float* __restrict__ in = jobs.j[k].src;
        u16* __restrict__ out = jobs.j[k].dst;
        const int n4 = jobs.j[k].n4;
        for (int i = t0; i < n4; i += stride) {
            float4 v = ((const float4*)in)[i];
            ushort4 o;
            o.x = f2bf(v.x); o.y = f2bf(v.y); o.z = f2bf(v.z); o.w = f2bf(v.w);
            ((ushort4*)out)[i] = o;
        }
    }
}

// 1024x1024 f32 -> bf16 TRANSPOSE (out[k][j] = in[j][k]) for Wcomb prep
__global__ void transpose_bf_k(const float* __restrict__ in, u16* __restrict__ out) {
    __shared__ float t[16][17];
    const int tx = threadIdx.x & 15, ty = threadIdx.x >> 4;
    const int bx = blockIdx.x, by = blockIdx.y;
    t[ty][tx] = in[(size_t)(by * 16 + ty) * 1024 + bx * 16 + tx];
    __syncthreads();
    out[(size_t)(bx * 16 + ty) * 1024 + by * 16 + tx] = f2bf(t[tx][ty]);
}

// bcomb[o] = sum_j fcw[o][j]*bp[j] + fcb[o]  (f32; one wave per row)
__global__ void bcomb_k(const float* __restrict__ fcw, const float* __restrict__ bp,
                        const float* __restrict__ fcb, float* __restrict__ out) {
    const int row = blockIdx.x * 4 + (threadIdx.x >> 6);
    const int lane = threadIdx.x & 63;
    float s = 0.f;
#pragma unroll
    for (int i = 0; i < 16; ++i)
        s += fcw[(size_t)row * 1024 + (i << 6) + lane] * bp[(i << 6) + lane];
#pragma unroll
    for (int off = 1; off < 64; off <<= 1) s += __shfl_xor(s, off);
    if (lane == 0) out[row] = s + fcb[row];
}

// both bias3072 vectors in one launch: [qb | zeros | vb] for temporal+spatial
__global__ void bias3x2_k(const float* __restrict__ qbt, const float* __restrict__ vbt,
                          const float* __restrict__ qbs, const float* __restrict__ vbs,
                          float* __restrict__ dt, float* __restrict__ ds) {
    const int i = blockIdx.x * 256 + threadIdx.x;
    if (i >= 3072) return;
    dt[i] = (i < 1024) ? qbt[i] : (i < 2048) ? 0.0f : vbt[i - 2048];
    ds[i] = (i < 1024) ? qbs[i] : (i < 2048) ? 0.0f : vbs[i - 2048];
}

// ---------------------------------------------------------------------------
// LayerNorm (one wave per row of 1024), gathers per stage, writes bf16.
// MODE 0: temporal (src=x, row r=b*1568+n*8+t  <- x[b][t][n][:])
// MODE 1: spatial  (src=xt_f, src2=cls_token; r=s2*197+i)
// ---------------------------------------------------------------------------
template<int MODE>
__global__ void ln_k(const float* __restrict__ src, const float* __restrict__ src2,
                     const float* __restrict__ g, const float* __restrict__ bt,
                     u16* __restrict__ out, int rows) {
    const int r = (blockIdx.x << 2) + (threadIdx.x >> 6);
    const int lane = threadIdx.x & 63;
    if (r >= rows) return;
    const float* srow;
    if constexpr (MODE == 0) {
        int b = r / kNT, rem = r - b * kNT, n = rem >> 3, t = rem & 7;
        srow = src + (((size_t)((b * 8 + t) * 196 + n)) << 10);
    } else {
        int s2 = r / kSeqS, i = r - s2 * kSeqS, b = s2 >> 3, t = s2 & 7;
        srow = (i == 0) ? (src2 + ((size_t)b << 10))
                        : (src + (((size_t)(b * kNT + ((i - 1) << 3) + t)) << 10));
    }
    float4 v[4]; float s = 0.f, ss = 0.f;
#pragma unroll
    for (int j = 0; j < 4; ++j) {
        v[j] = *(const float4*)&srow[((j << 6) + lane) << 2];
        s  += v[j].x + v[j].y + v[j].z + v[j].w;
        ss += v[j].x * v[j].x + v[j].y * v[j].y + v[j].z * v[j].z + v[j].w * v[j].w;
    }
#pragma unroll
    for (int off = 1; off < 64; off <<= 1) { s += __shfl_xor(s, off); ss += __shfl_xor(ss, off); }
    const float mean = s * (1.f / 1024.f);
    const float rstd = rsqrtf(ss * (1.f / 1024.f) - mean * mean + 1e-5f);
#pragma unroll
    for (int j = 0; j < 4; ++j) {
        const int c = ((j << 6) + lane) << 2;
        float4 gg = *(const float4*)&g[c];
        float4 bb = *(const float4*)&bt[c];
        ushort4 o;
        o.x = f2bf((v[j].x - mean) * rstd * gg.x + bb.x);
        o.y = f2bf((v[j].y - mean) * rstd * gg.y + bb.y);
        o.z = f2bf((v[j].z - mean) * rstd * gg.z + bb.z);
        o.w = f2bf((v[j].w - mean) * rstd * gg.w + bb.w);
        *(ushort4*)&out[((size_t)r << 10) + c] = o;
    }
}

// ---------------------------------------------------------------------------
// Fused build_x2 + LayerNorm(n2): one block per x2 row.
// Writes x2 (f32, fc2 residual) AND ln(x2) (bf16, fc1 input) in one pass.
// ---------------------------------------------------------------------------
__global__ void bx2ln_k(const float* __restrict__ xt, const float* __restrict__ xs,
                        const float* __restrict__ cls, const float* __restrict__ cm,
                        const float* __restrict__ g, const float* __restrict__ bt,
                        float* __restrict__ x2, u16* __restrict__ out) {
    __shared__ float red[2][4];
    const int r = blockIdx.x;
    const int tid = threadIdx.x, lane = tid & 63, wave = tid >> 6;
    const int c = tid << 2;
    const int b = r / 1569, i = r - b * 1569;
    const float* pa; const float* pb;
    if (i == 0) {
        pa = cls + ((size_t)b << 10) + c;
        pb = cm + ((size_t)b << 10) + c;
    } else {
        const int jj = i - 1, n = jj >> 3, t = jj & 7;
        pa = xt + (((size_t)(b * 1568 + jj)) << 10) + c;
        pb = xs + (((size_t)((b * 8 + t) * kSeqS + 1 + n)) << 10) + c;
    }
    const float4 va = *(const float4*)pa;
    const float4 vb = *(const float4*)pb;
    float4 vo;
    vo.x = va.x + vb.x; vo.y = va.y + vb.y; vo.z = va.z + vb.z; vo.w = va.w + vb.w;
    *(float4*)&x2[((size_t)r << 10) + c] = vo;
    float s  = vo.x + vo.y + vo.z + vo.w;
    float ss = vo.x * vo.x + vo.y * vo.y + vo.z * vo.z + vo.w * vo.w;
#pragma unroll
    for (int off = 1; off < 64; off <<= 1) { s += __shfl_xor(s, off); ss += __shfl_xor(ss, off); }
    if (lane == 0) { red[0][wave] = s; red[1][wave] = ss; }
    __syncthreads();
    s  = red[0][0] + red[0][1] + red[0][2] + red[0][3];
    ss = red[1][0] + red[1][1] + red[1][2] + red[1][3];
    const float mean = s * (1.f / 1024.f);
    const float rstd = rsqrtf(ss * (1.f / 1024.f) - mean * mean + 1e-5f);
    const float4 gg = *(const float4*)&g[c];
    const float4 bb = *(const float4*)&bt[c];
    ushort4 o;
    o.x = f2bf((vo.x - mean) * rstd * gg.x + bb.x);
    o.y = f2bf((vo.y - mean) * rstd * gg.y + bb.y);
    o.z = f2bf((vo.z - mean) * rstd * gg.z + bb.z);
    o.w = f2bf((vo.w - mean) * rstd * gg.w + bb.w);
    *(ushort4*)&out[((size_t)r << 10) + c] = o;
}

// ---------------------------------------------------------------------------
// GEMM: C[M,N] = A[M,K](bf16) @ W[N,K]^T(bf16) + bias, TMx128 tile, BK=32,
// 4 waves (2x2), 16x16x32 bf16 MFMA, global_load_lds staging, 2 barriers per
// K-step (R2 structure). Conflict-free LDS swizzle (R5) + XCD-chunked block
// swizzle (R7; bijective, all grids % 8 == 0).
// MODE 0: out bf16               MODE 1: out f32
// MODE 2: GELU(fast) -> bf16     MODE 3: + x-perm residual -> f32
// MODE 4: + x2 residual -> scatter to d_out (xo | cls_out), f32
// ---------------------------------------------------------------------------
template<int MODE, int TM>
__global__ void gemm_bt(
        const u16* __restrict__ A, const u16* __restrict__ W,
        const float* __restrict__ bias,
        u16* __restrict__ outB, float* __restrict__ outF,
        const float* __restrict__ resid, float* __restrict__ dout,
        int M, int N, int K) {
    constexpr int MF  = TM / 32;    // per-wave M fragments
    constexpr int NCA = TM / 64;    // A staging chunks per lane
    __shared__ __align__(16) u16 As[TM * 32];
    __shared__ __align__(16) u16 Bs[128 * 32];
    const int tid  = threadIdx.x;
    const int lane = tid & 63, wave = tid >> 6;
    const int lo = lane & 15, hi = lane >> 4;
    const int wr = wave >> 1, wc = wave & 1;

    // XCD-chunked swizzle (all grids launched with nwg % 8 == 0)
    const int nbx = gridDim.x;
    const int nwg = nbx * gridDim.y;
    int bid = blockIdx.y * nbx + blockIdx.x;
    {
        const int per = nwg >> 3;
        bid = (bid & 7) * per + (bid >> 3);
    }
    const int row0 = (bid / nbx) * TM, col0 = (bid % nbx) << 7;

    // staging: chunk c (16B) -> LDS row c>>2, phys slot c&3; logical k-sub
    // j = (c&3) ^ ((row>>1)&3) carried on the global source address.
    const u16* aP[NCA]; const u16* bP[2];
#pragma unroll
    for (int i = 0; i < NCA; ++i) {
        const int c = wave * TM + (i << 6) + lane;
        const int row = c >> 2;
        const int jl = (((c & 3) ^ ((c >> 3) & 3)) << 3);
        int ar = row0 + row; if (ar > M - 1) ar = M - 1;
        aP[i] = A + (size_t)ar * K + jl;
    }
#pragma unroll
    for (int i = 0; i < 2; ++i) {
        const int c = (wave << 7) + (i << 6) + lane;
        const int row = c >> 2;
        const int jl = (((c & 3) ^ ((c >> 3) & 3)) << 3);
        int br = col0 + row; if (br > N - 1) br = N - 1;
        bP[i] = W + (size_t)br * K + jl;
    }

    f32x4 acc[MF][4] = {};
    const int sl = (hi ^ ((lo >> 1) & 3)) << 3;   // swizzled 16B read slot

    for (int k0 = 0; k0 < K; k0 += 32) {
#pragma unroll
        for (int i = 0; i < NCA; ++i)
            gll16(aP[i] + k0, &As[wave * (TM * 8) + (i << 9)]);
#pragma unroll
        for (int i = 0; i < 2; ++i)
            gll16(bP[i] + k0, &Bs[(wave << 10) + (i << 9)]);
        __syncthreads();   // implicit vmcnt(0): tile ready
        bf16x8 af[MF], bfr[4];
#pragma unroll
        for (int m = 0; m < MF; ++m)
            af[m] = *(const bf16x8*)&As[((wr * (TM / 2) + (m << 4) + lo) << 5) + sl];
#pragma unroll
        for (int n = 0; n < 4; ++n)
            bfr[n] = *(const bf16x8*)&Bs[(((wc << 6) + (n << 4) + lo) << 5) + sl];
#pragma unroll
        for (int m = 0; m < MF; ++m)
#pragma unroll
            for (int n = 0; n < 4; ++n)
                acc[m][n] = __builtin_amdgcn_mfma_f32_16x16x32_bf16(af[m], bfr[n], acc[m][n], 0, 0, 0);
        __syncthreads();   // protect LDS before next stage
    }

#pragma unroll
    for (int m = 0; m < MF; ++m) {
        const int rb = row0 + wr * (TM / 2) + (m << 4) + (hi << 2);
#pragma unroll
        for (int n = 0; n < 4; ++n) {
            const int c = col0 + (wc << 6) + (n << 4) + lo;
            const float bc = bias[c];
#pragma unroll
            for (int j = 0; j < 4; ++j) {
                const int r = rb + j;
                if (r >= M) continue;
                float v = acc[m][n][j] + bc;
                if constexpr (MODE == 2) v = gelu_fast(v);
                if constexpr (MODE == 3) {
                    int b = r / 1568, rem = r - b * 1568, nn = rem >> 3, tt = rem & 7;
                    v += resid[(((size_t)((b * 8 + tt) * 196 + nn)) << 10) + c];
                }
                if constexpr (MODE == 0 || MODE == 2) {
                    outB[(size_t)r * N + c] = f2bf(v);
                } else if constexpr (MODE == 1 || MODE == 3) {
                    outF[(size_t)r * N + c] = v;
                } else {  // MODE 4
                    v += resid[((size_t)r << 10) + c];
                    int b = r / 1569, i = r - b * 1569;
                    if (i == 0) dout[kXO + ((size_t)b << 10) + c] = v;
                    else {
                        int jj = i - 1, nn = jj >> 3, tt = jj & 7;
                        dout[(((size_t)((b * 8 + tt) * 196 + nn)) << 10) + c] = v;
                    }
                }
            }
        }
    }
}

// ---------------------------------------------------------------------------
// Temporal attention: T=8, HD=64. One wave per (seq, head); 4 per block.
// R11: staging vectorized (3 bf16x8 loads/lane, part uniform per iteration).
// ---------------------------------------------------------------------------
__global__ void attn_a_k(const u16* __restrict__ qkv, u16* __restrict__ o) {
    __shared__ float lq[4][8][65], lk[4][8][65], lv[4][8][65];
    __shared__ float al[4][64];
    const int lane = threadIdx.x & 63, wave = threadIdx.x >> 6;
    const int p = (blockIdx.x << 2) + wave;   // 0..12543
    const int s = p >> 4, h = p & 15;
    const u16* base = qkv + (size_t)s * 24576 + (h << 6);
#pragma unroll
    for (int k = 0; k < 3; ++k) {
        const int t = lane >> 3, d8 = (lane & 7) << 3;
        union { bf16x8 v; u16 e[8]; } pk;
        pk.v = *(const bf16x8*)&base[(size_t)t * 3072 + (k << 10) + d8];
        float* dst = (k == 0) ? &lq[wave][t][d8] : (k == 1) ? &lk[wave][t][d8] : &lv[wave][t][d8];
#pragma unroll
        for (int z = 0; z < 8; ++z) dst[z] = bf2f(pk.e[z]);
    }
    __syncthreads();
    const int qi = lane >> 3, kj = lane & 7;
    float dot = 0.f;
#pragma unroll
    for (int d = 0; d < 64; ++d) dot += lq[wave][qi][d] * lk[wave][kj][d];
    dot *= SCALE;
    float m = dot;
    m = fmaxf(m, __shfl_xor(m, 1));
    m = fmaxf(m, __shfl_xor(m, 2));
    m = fmaxf(m, __shfl_xor(m, 4));
    const float e = expf(dot - m);
    float sm = e;
    sm += __shfl_xor(sm, 1);
    sm += __shfl_xor(sm, 2);
    sm += __shfl_xor(sm, 4);
    al[wave][lane] = e / sm;
    __syncthreads();
    u16* orow = o + (size_t)s * 8192 + (h << 6) + lane;
#pragma unroll
    for (int ii = 0; ii < 8; ++ii) {
        float accv = 0.f;
#pragma unroll
        for (int jj = 0; jj < 8; ++jj) accv += al[wave][(ii << 3) + jj] * lv[wave][jj][lane];
        orow[(size_t)ii * 1024] = f2bf(accv);
    }
}

// ---------------------------------------------------------------------------
// Spatial attention (MFMA flash-style): seq 197, HD=64.
// One block (4 waves) per (s2, head); waves own independent 16-row q-tiles;
// NO barriers in the main loop. See R2-R10 history.
// LDS: 64*232 + 4*16*232 u16 = 59,392 B  (2 blocks/CU).
// ---------------------------------------------------------------------------
__global__ __launch_bounds__(256, 2) void attn_s_mfma(const u16* __restrict__ qkv,
                                                      u16* __restrict__ o) {
    __shared__ __align__(16) u16 SM[29696];  // Vt[64][232] | P: 4 x [16][232]
    u16* __restrict__ Vt = SM;
    const int tid = threadIdx.x, lane = tid & 63, wave = tid >> 6;
    const int lo = lane & 15, hi = lane >> 4;
    u16* __restrict__ Pw = SM + 14848 + wave * 3712;
    const int s2 = blockIdx.x >> 4, h = blockIdx.x & 15;
    const u16* __restrict__ base = qkv + (size_t)s2 * (kSeqS * 3072) + (h << 6);

    // ---- stage V^T: Vt[d][k], k rows clamped at 196 (finite pad; P=0 there)
    for (int u = tid; u < 26 * 64; u += 256) {
        const int d = u & 63, k0 = (u >> 6) << 3;
        union { bf16x8 v; u16 e[8]; } pk;
#pragma unroll
        for (int i = 0; i < 8; ++i) {
            int kr = k0 + i; if (kr > 196) kr = 196;
            pk.e[i] = base[(size_t)kr * 3072 + 2048 + d];
        }
        *(bf16x8*)&Vt[d * 232 + k0] = pk.v;
    }
    // zero Vt cols 208..223 (PV kc=6 reads up to col 223; must be finite)
    for (int u = tid; u < 1024; u += 256)
        Vt[(u >> 4) * 232 + 208 + (u & 15)] = 0;
    // zero P cols 208..223 (written once; softmax rewrites only cols 0..207)
    for (int u = lane; u < 256; u += 64)
        Pw[(u >> 4) * 232 + 208 + (u & 15)] = 0;
    __syncthreads();

    for (int qt = wave; qt < 13; qt += 4) {
        int qr = qt * 16 + lo; if (qr > 196) qr = 196;
        const u16* qp = base + (size_t)qr * 3072;
        const bf16x8 aq0 = *(const bf16x8*)&qp[hi << 3];
        const bf16x8 aq1 = *(const bf16x8*)&qp[32 + (hi << 3)];

        // ---- S = Q K^T (scaled), 13 k-tiles x K=64
        f32x4 s[13];
#pragma unroll
        for (int kt = 0; kt < 13; ++kt) {
            int kr = kt * 16 + lo; if (kr > 196) kr = 196;
            const u16* kp = base + (size_t)kr * 3072 + 1024;
            const bf16x8 bk0 = *(const bf16x8*)&kp[hi << 3];
            const bf16x8 bk1 = *(const bf16x8*)&kp[32 + (hi << 3)];
            f32x4 acc = {};
            acc = __builtin_amdgcn_mfma_f32_16x16x32_bf16(aq0, bk0, acc, 0, 0, 0);
            acc = __builtin_amdgcn_mfma_f32_16x16x32_bf16(aq1, bk1, acc, 0, 0, 0);
            s[kt] = acc * SCALE;
        }
        if (lo > 4) s[12] = (f32x4){-1e30f, -1e30f, -1e30f, -1e30f};  // mask k>=197

        // ---- softmax over k (per output row hi*4+j)
        float inv[4];
#pragma unroll
        for (int j = 0; j < 4; ++j) {
            float m = s[0][j];
#pragma unroll
            for (int kt = 1; kt < 13; ++kt) m = fmaxf(m, s[kt][j]);
            m = fmaxf(m, __shfl_xor(m, 1));
            m = fmaxf(m, __shfl_xor(m, 2));
            m = fmaxf(m, __shfl_xor(m, 4));
            m = fmaxf(m, __shfl_xor(m, 8));
            float sum = 0.f;
#pragma unroll
            for (int kt = 0; kt < 13; ++kt) {
                const float e = __expf(s[kt][j] - m);
                s[kt][j] = e;
                sum += e;
            }
            sum += __shfl_xor(sum, 1);
            sum += __shfl_xor(sum, 2);
            sum += __shfl_xor(sum, 4);
            sum += __shfl_xor(sum, 8);
            inv[j] = 1.f / sum;
        }

        // ---- P (unnormalized) -> per-wave LDS, bf16
#pragma unroll
        for (int kt = 0; kt < 13; ++kt)
#pragma unroll
            for (int j = 0; j < 4; ++j)
                Pw[((hi << 2) + j) * 232 + kt * 16 + lo] = f2bf(s[kt][j]);

        // ---- O = P V  (7 K=32 chunks; chunk 6 uses zero-padded P/V cols)
        f32x4 o4[4] = {};
#pragma unroll
        for (int kc = 0; kc < 7; ++kc) {
            const bf16x8 pa = *(const bf16x8*)&Pw[lo * 232 + kc * 32 + (hi << 3)];
#pragma unroll
            for (int dt = 0; dt < 4; ++dt) {
                const bf16x8 vf = *(const bf16x8*)&Vt[(dt * 16 + lo) * 232 + kc * 32 + (hi << 3)];
                o4[dt] = __builtin_amdgcn_mfma_f32_16x16x32_bf16(pa, vf, o4[dt], 0, 0, 0);
            }
        }

        // ---- write (apply 1/sum in f32 here)
#pragma unroll
        for (int j = 0; j < 4; ++j) {
            const int q = qt * 16 + (hi << 2) + j;
            if (q > 196) continue;
            u16* orow = o + (((size_t)(s2 * kSeqS + q)) << 10) + (h << 6);
#pragma unroll
            for (int dt = 0; dt < 4; ++dt)
                orow[dt * 16 + lo] = f2bf(o4[dt][j] * inv[j]);
        }
    }
}

// cls_m[b][c] = mean over t of xs[(b*8+t)*197 + 0][c]
__global__ void clsm_k(const float* __restrict__ xs, float* __restrict__ cm) {
    const int idx = blockIdx.x * 256 + threadIdx.x;
    if (idx >= 4096) return;
    const int b = idx >> 10, c = idx & 1023;
    float s = 0.f;
#pragma unroll
    for (int t = 0; t < 8; ++t) s += xs[(((size_t)(b * 8 + t)) * kSeqS) * 1024 + c];
    cm[idx] = s * 0.125f;
}

// ---------------------------------------------------------------------------
extern "C" void kernel_launch(void* const* d_in, const int* in_sizes, int n_in,
                              void* d_out, int out_size, void* d_ws, size_t ws_size,
                              hipStream_t stream) {
    const float* x       = (const float*)d_in[0];
    const float* cls     = (const float*)d_in[1];
    const float* tln_g   = (const float*)d_in[2];
    const float* tln_b   = (const float*)d_in[3];
    const float* t_wqkv  = (const float*)d_in[4];
    const float* t_qb    = (const float*)d_in[5];
    const float* t_vb    = (const float*)d_in[6];
    const float* t_wproj = (const float*)d_in[7];
    const float* t_bproj = (const float*)d_in[8];
    const float* t_fc_w  = (const float*)d_in[9];
    const float* t_fc_b  = (const float*)d_in[10];
    const float* n1_g    = (const float*)d_in[11];
    const float* n1_b    = (const float*)d_in[12];
    const float* s_wqkv  = (const float*)d_in[13];
    const float* s_qb    = (const float*)d_in[14];
    const float* s_vb    = (const float*)d_in[15];
    const float* s_wproj = (const float*)d_in[16];
    const float* s_bproj = (const float*)d_in[17];
    const float* n2_g    = (const float*)d_in[18];
    const float* n2_b    = (const float*)d_in[19];
    const float* fc1_w   = (const float*)d_in[20];
    const float* fc1_b   = (const float*)d_in[21];
    const float* fc2_w   = (const float*)d_in[22];
    const float* fc2_b   = (const float*)d_in[23];
    float* dout = (float*)d_out;
    char* ws = (char*)d_ws;

    size_t off = 0;
    auto alloc = [&](size_t bytes) { size_t o = off; off += (bytes + 255) & ~(size_t)255; return o; };

    u16* t_wqkv_bf  = (u16*)(ws + alloc(3145728ull * 2));
    u16* wpT_bf     = (u16*)(ws + alloc(1048576ull * 2));   // wp^T (for Wcomb prep)
    u16* t_fcw_bf   = (u16*)(ws + alloc(1048576ull * 2));
    u16* s_wqkv_bf  = (u16*)(ws + alloc(3145728ull * 2));
    u16* s_wproj_bf = (u16*)(ws + alloc(1048576ull * 2));
    u16* fc1_bf     = (u16*)(ws + alloc(4194304ull * 2));
    u16* fc2_bf     = (u16*)(ws + alloc(4194304ull * 2));
    u16* ln_bf      = (u16*)(ws + alloc((size_t)kRowsS * 1024 * 2));
    u16* qkv_bf     = (u16*)(ws + alloc((size_t)kRowsS * 3072 * 2));
    u16* o_bf       = (u16*)(ws + alloc((size_t)kRowsS * 1024 * 2));
    u16* h1_bf      = qkv_bf;  // fc1 out (6276*4096*2 B) aliases dead qkv+o regions
    u16* wcomb_bf   = (u16*)(ws + alloc(1048576ull * 2));   // Wfc·Wp, bf16 [out][k]
    float* xt_f     = (float*)(ws + alloc((size_t)kRowsA * 1024 * 4));
    float* xs_f     = (float*)(ws + alloc((size_t)kRowsS * 1024 * 4));
    float* x2_f     = (float*)(ws + alloc((size_t)kRowsC * 1024 * 4));
    float* bias_t   = (float*)(ws + alloc(3072 * 4));
    float* bias_s   = (float*)(ws + alloc(3072 * 4));
    float* clsm     = (float*)(ws + alloc(4096 * 4));
    float* bcomb    = (float*)(ws + alloc(1024 * 4));
    (void)ws_size; (void)in_sizes; (void)n_in; (void)out_size;

    // weights -> bf16: all six conversions in ONE launch (R11)
    ConvJobs6 jobs;
    jobs.j[0] = { t_wqkv, t_wqkv_bf, 786432 };
    jobs.j[1] = { t_fc_w, t_fcw_bf,  262144 };
    jobs.j[2] = { s_wqkv, s_wqkv_bf, 786432 };
    jobs.j[3] = { s_wproj, s_wproj_bf, 262144 };
    jobs.j[4] = { fc1_w, fc1_bf, 1048576 };
    jobs.j[5] = { fc2_w, fc2_bf, 1048576 };
    convw6_k<<<dim3(2048), dim3(256), 0, stream>>>(jobs);
    bias3x2_k<<<dim3(12), dim3(256), 0, stream>>>(t_qb, t_vb, s_qb, s_vb, bias_t, bias_s);
    transpose_bf_k<<<dim3(64, 64), dim3(256), 0, stream>>>(t_wproj, wpT_bf);
    bcomb_k<<<dim3(256), dim3(256), 0, stream>>>(t_fc_w, t_bproj, t_fc_b, bcomb);
    // Wcomb[o][k] = sum_j fc_w[o][j] * wp[j][k]  (A=fc_w, W=wp^T; zero bias)
    gemm_bt<0, 128><<<dim3(8, 8), dim3(256), 0, stream>>>(
        t_fcw_bf, wpT_bf, bias_t + 1024, wcomb_bf, nullptr, nullptr, nullptr, 1024, 1024, 1024);

    // ---- temporal branch ----
    ln_k<0><<<dim3(kRowsA / 4), dim3(256), 0, stream>>>(x, nullptr, tln_g, tln_b, ln_bf, kRowsA);
    gemm_bt<0, 128><<<dim3(24, 49), dim3(256), 0, stream>>>(ln_bf, t_wqkv_bf, bias_t, qkv_bf, nullptr, nullptr, nullptr, kRowsA, 3072, 1024);
    attn_a_k<<<dim3(3136), dim3(256), 0, stream>>>(qkv_bf, o_bf);
    // fused proj+fc: xt = o @ Wcomb^T + bcomb + x_perm
    gemm_bt<3, 64><<<dim3(8, 98), dim3(256), 0, stream>>>(o_bf, wcomb_bf, bcomb, nullptr, xt_f, x, nullptr, kRowsA, 1024, 1024);

    // ---- spatial branch ----
    ln_k<1><<<dim3(kRowsS / 4), dim3(256), 0, stream>>>(xt_f, cls, n1_g, n1_b, ln_bf, kRowsS);
    gemm_bt<0, 128><<<dim3(24, 50), dim3(256), 0, stream>>>(ln_bf, s_wqkv_bf, bias_s, qkv_bf, nullptr, nullptr, nullptr, kRowsS, 3072, 1024);
    attn_s_mfma<<<dim3(512), dim3(256), 0, stream>>>(qkv_bf, o_bf);
    gemm_bt<1, 64><<<dim3(8, 99), dim3(256), 0, stream>>>(o_bf, s_wproj_bf, s_bproj, nullptr, xs_f, nullptr, nullptr, kRowsS, 1024, 1024);
    clsm_k<<<dim3(16), dim3(256), 0, stream>>>(xs_f, clsm);
    // fused build_x2 + ln(n2): writes x2_f (f32) and ln_bf (bf16) in one pass
    bx2ln_k<<<dim3(kRowsC), dim3(256), 0, stream>>>(xt_f, xs_f, cls, clsm, n2_g, n2_b, x2_f, ln_bf);

    // ---- MLP ----
    // fc1: TM=128 + fast GELU
    gemm_bt<2, 128><<<dim3(32, 50), dim3(256), 0, stream>>>(ln_bf, fc1_bf, fc1_b, h1_bf, nullptr, nullptr, nullptr, kRowsC, 4096, 1024);
    // fc2: TM=64 -> 792 blocks (3.1/CU)
    gemm_bt<4, 64><<<dim3(8, 99), dim3(256), 0, stream>>>(h1_bf, fc2_bf, fc2_b, nullptr, nullptr, x2_f, dout, kRowsC, 1024, 4096);
}